// Round 1
// baseline (1454.523 us; speedup 1.0000x reference)
//
#include <hip/hip_runtime.h>
#include <cstdint>
#include <cstddef>

// GraphRec forward, fp32 vector baseline.
// B=512, N=30, d=64. Heavy work: gv-MLP3 over B*N*N rows (computed twice:
// score pass + weighted-sum pass, to avoid a 118 MB xoa buffer).

#define GB 512   // batch
#define GN 30    // neighbors
#define GD 64    // feature dim

// ---------- small helpers ----------
__device__ __forceinline__ unsigned short f2bf(float x) {
  union { float f; uint32_t u; } c; c.f = x;
  uint32_t r = c.u + 0x7fffu + ((c.u >> 16) & 1u);   // RTN-even
  return (unsigned short)(r >> 16);
}
__device__ __forceinline__ float bf2f(unsigned short b) {
  union { float f; uint32_t u; } c; c.u = ((uint32_t)b) << 16; return c.f;
}
__device__ __forceinline__ float wave_sum(float v) {
#pragma unroll
  for (int off = 32; off >= 1; off >>= 1) v += __shfl_xor(v, off, 64);
  return v;
}

// ---------- fused 3-layer MLP on R gathered rows (one wave) ----------
// x = concat(A_row, B_row) [128]; h1 = relu(x@W1+b1); h2 = relu(h1@W2+b2);
// acc = h2@W3 + b3 (no relu).  Weights live in LDS as bf16. hbw is this
// wave's private LDS scratch ([R][64]); on return it holds h2.
template <int R>
__device__ __forceinline__ void mlp3_rows(
    int lane, const float* const* pa, const float* const* pb,
    const unsigned short* w1s, const unsigned short* w2s, const unsigned short* w3s,
    const float* b1s, const float* b2s, const float* b3s,
    float (*hbw)[GD], float* acc) {
#pragma unroll
  for (int r = 0; r < R; r++) acc[r] = b1s[lane];
#pragma unroll 8
  for (int k = 0; k < 64; k++) {
    float w = bf2f(w1s[k * 64 + lane]);
#pragma unroll
    for (int r = 0; r < R; r++) acc[r] = fmaf(pa[r][k], w, acc[r]);
  }
#pragma unroll 8
  for (int k = 0; k < 64; k++) {
    float w = bf2f(w1s[(64 + k) * 64 + lane]);
#pragma unroll
    for (int r = 0; r < R; r++) acc[r] = fmaf(pb[r][k], w, acc[r]);
  }
#pragma unroll
  for (int r = 0; r < R; r++) hbw[r][lane] = fmaxf(acc[r], 0.f);
  // layer 2
#pragma unroll
  for (int r = 0; r < R; r++) acc[r] = b2s[lane];
#pragma unroll
  for (int kc = 0; kc < 16; kc++) {
    float w0 = bf2f(w2s[(kc * 4 + 0) * 64 + lane]);
    float w1 = bf2f(w2s[(kc * 4 + 1) * 64 + lane]);
    float w2 = bf2f(w2s[(kc * 4 + 2) * 64 + lane]);
    float w3 = bf2f(w2s[(kc * 4 + 3) * 64 + lane]);
#pragma unroll
    for (int r = 0; r < R; r++) {
      float4 x = *(const float4*)(&hbw[r][kc * 4]);
      acc[r] = fmaf(x.x, w0, fmaf(x.y, w1, fmaf(x.z, w2, fmaf(x.w, w3, acc[r]))));
    }
  }
#pragma unroll
  for (int r = 0; r < R; r++) hbw[r][lane] = fmaxf(acc[r], 0.f);
  // layer 3 (no relu)
#pragma unroll
  for (int r = 0; r < R; r++) acc[r] = b3s[lane];
#pragma unroll
  for (int kc = 0; kc < 16; kc++) {
    float w0 = bf2f(w3s[(kc * 4 + 0) * 64 + lane]);
    float w1 = bf2f(w3s[(kc * 4 + 1) * 64 + lane]);
    float w2 = bf2f(w3s[(kc * 4 + 2) * 64 + lane]);
    float w3 = bf2f(w3s[(kc * 4 + 3) * 64 + lane]);
#pragma unroll
    for (int r = 0; r < R; r++) {
      float4 x = *(const float4*)(&hbw[r][kc * 4]);
      acc[r] = fmaf(x.x, w0, fmaf(x.y, w1, fmaf(x.z, w2, fmaf(x.w, w3, acc[r]))));
    }
  }
}

// ---------- out[r][j] = sum_k tab[idx[r]][k] * W[k][j]  (first 64 rows of W) ----------
__global__ __launch_bounds__(256, 4) void k_rowlin(
    int M, const float* __restrict__ tab, const int* __restrict__ idx,
    const float* __restrict__ W, float* __restrict__ out) {
  __shared__ float ws[64 * 64];
  for (int i = threadIdx.x; i < 64 * 64; i += 256) ws[i] = W[i];
  __syncthreads();
  const int lane = threadIdx.x & 63, wave = threadIdx.x >> 6;
  int base0 = (blockIdx.x * 4 + wave) * 8;
  if (base0 >= M) return;
  const float* p[8];
#pragma unroll
  for (int r = 0; r < 8; r++) {
    int ia = __builtin_amdgcn_readfirstlane(idx[base0 + r]);
    p[r] = tab + (size_t)ia * 64;
  }
  float acc[8];
#pragma unroll
  for (int r = 0; r < 8; r++) acc[r] = 0.f;
#pragma unroll 8
  for (int k = 0; k < 64; k++) {
    float w = ws[k * 64 + lane];
#pragma unroll
    for (int r = 0; r < 8; r++) acc[r] = fmaf(p[r][k], w, acc[r]);
  }
#pragma unroll
  for (int r = 0; r < 8; r++) out[(size_t)(base0 + r) * 64 + lane] = acc[r];
}

// ---------- generic MLP3 over M rows: x = concat(tabA[idxA[r]], tabB[idxB[r]]) ----------
__global__ __launch_bounds__(512, 2) void k_mlp3(
    int M,
    const float* __restrict__ tabA, const int* __restrict__ idxA,
    const float* __restrict__ tabB, const int* __restrict__ idxB,
    const float* __restrict__ W1, const float* __restrict__ b1,
    const float* __restrict__ W2, const float* __restrict__ b2,
    const float* __restrict__ W3, const float* __restrict__ b3,
    float* __restrict__ out) {
  __shared__ unsigned short w1s[128 * 64], w2s[64 * 64], w3s[64 * 64];
  __shared__ float b1s[64], b2s[64], b3s[64];
  __shared__ float hb[8][8][GD];
  for (int i = threadIdx.x; i < 128 * 64; i += 512) w1s[i] = f2bf(W1[i]);
  for (int i = threadIdx.x; i < 64 * 64; i += 512) { w2s[i] = f2bf(W2[i]); w3s[i] = f2bf(W3[i]); }
  if (threadIdx.x < 64) { b1s[threadIdx.x] = b1[threadIdx.x]; b2s[threadIdx.x] = b2[threadIdx.x]; b3s[threadIdx.x] = b3[threadIdx.x]; }
  __syncthreads();
  const int lane = threadIdx.x & 63, wave = threadIdx.x >> 6;
  for (int base = blockIdx.x * 64; base < M; base += gridDim.x * 64) {
    int rb = base + wave * 8;
    const float* pa[8]; const float* pb[8];
#pragma unroll
    for (int r = 0; r < 8; r++) {
      int row = rb + r;
      int ia = idxA ? idxA[row] : row;
      pa[r] = tabA + (size_t)__builtin_amdgcn_readfirstlane(ia) * 64;
      int ib = idxB ? idxB[row] : row;
      pb[r] = tabB + (size_t)__builtin_amdgcn_readfirstlane(ib) * 64;
    }
    float acc[8];
    mlp3_rows<8>(lane, pa, pb, w1s, w2s, w3s, b1s, b2s, b3s, hb[wave], acc);
#pragma unroll
    for (int r = 0; r < 8; r++) out[(size_t)(rb + r) * 64 + lane] = acc[r];
  }
}

// ---------- attention scores for [B*N] rows: s = relu(selfW[b] + X@W1b + b1) @ W2 + b2 ----------
__global__ __launch_bounds__(256, 4) void k_score(
    int M, const float* __restrict__ selfW, const float* __restrict__ X,
    const float* __restrict__ W1b, const float* __restrict__ b1,
    const float* __restrict__ W2, const float* __restrict__ b2,
    float* __restrict__ sOut) {
  __shared__ float ws[64 * 64];
  __shared__ float w2s[64], b1s[64];
  for (int i = threadIdx.x; i < 64 * 64; i += 256) ws[i] = W1b[i];
  if (threadIdx.x < 64) { w2s[threadIdx.x] = W2[threadIdx.x]; b1s[threadIdx.x] = b1[threadIdx.x]; }
  __syncthreads();
  const int lane = threadIdx.x & 63, wave = threadIdx.x >> 6;
  int rb = (blockIdx.x * 4 + wave) * 8;
  if (rb >= M) return;
  const float* px[8]; float acc[8];
#pragma unroll
  for (int r = 0; r < 8; r++) {
    int row = rb + r;
    px[r] = X + (size_t)row * 64;
    acc[r] = b1s[lane] + selfW[(size_t)(row / GN) * 64 + lane];
  }
#pragma unroll 8
  for (int k = 0; k < 64; k++) {
    float w = ws[k * 64 + lane];
#pragma unroll
    for (int r = 0; r < 8; r++) acc[r] = fmaf(px[r][k], w, acc[r]);
  }
  float bb2 = b2[0];
#pragma unroll
  for (int r = 0; r < 8; r++) {
    float v = fmaxf(acc[r], 0.f) * w2s[lane];
    v = wave_sum(v);
    if (lane == 0) sOut[rb + r] = v + bb2;
  }
}

// ---------- softmax over the batch axis (column c of a [512][C] array), in place ----------
__global__ __launch_bounds__(256) void k_softmax_col(float* __restrict__ s, int C) {
  int c = blockIdx.x, t = threadIdx.x;
  int lane = t & 63, wave = t >> 6;
  float v0 = s[(size_t)t * C + c];
  float v1 = s[(size_t)(t + 256) * C + c];
  float m = fmaxf(v0, v1);
#pragma unroll
  for (int off = 32; off >= 1; off >>= 1) m = fmaxf(m, __shfl_xor(m, off, 64));
  __shared__ float rm[4], rs[4];
  if (lane == 0) rm[wave] = m;
  __syncthreads();
  float M4 = fmaxf(fmaxf(rm[0], rm[1]), fmaxf(rm[2], rm[3]));
  float e0 = expf(v0 - M4), e1 = expf(v1 - M4);
  float sm = wave_sum(e0 + e1);
  if (lane == 0) rs[wave] = sm;
  __syncthreads();
  float inv = 1.f / (rs[0] + rs[1] + rs[2] + rs[3]);
  s[(size_t)t * C + c] = e0 * inv;
  s[(size_t)(t + 256) * C + c] = e1 * inv;
}

// ---------- out[b] = relu( (sum_n alpha[b,n]*X[b,n,:]) @ W + bias ) ----------
__global__ __launch_bounds__(64) void k_wsum_lin(
    int C, const float* __restrict__ alpha, const float* __restrict__ X,
    const float* __restrict__ W, const float* __restrict__ bias,
    float* __restrict__ out) {
  int b = blockIdx.x, l = threadIdx.x;
  float t = 0.f;
  for (int n = 0; n < C; n++) t = fmaf(alpha[b * C + n], X[((size_t)b * C + n) * 64 + l], t);
  __shared__ float ts[64];
  ts[l] = t;  // single-wave block: DS ops are in program order
  float acc = bias[l];
#pragma unroll 8
  for (int k = 0; k < 64; k++) acc = fmaf(ts[k], W[k * 64 + l], acc);
  out[(size_t)b * 64 + l] = fmaxf(acc, 0.f);
}

// ---------- pass 1: xoa = gv-MLP3 row, fused attO score ----------
__global__ __launch_bounds__(512, 2) void k_xoa_pass1(
    const float* __restrict__ E_i, const float* __restrict__ E_r,
    const int* __restrict__ items, const int* __restrict__ items_r,
    const float* __restrict__ W1, const float* __restrict__ b1,
    const float* __restrict__ W2, const float* __restrict__ b2,
    const float* __restrict__ W3, const float* __restrict__ b3,
    const float* __restrict__ poW,
    const float* __restrict__ aW1b, const float* __restrict__ ab1,
    const float* __restrict__ aW2, const float* __restrict__ ab2,
    float* __restrict__ sOut) {
  __shared__ unsigned short w1s[128 * 64], w2s[64 * 64], w3s[64 * 64], was[64 * 64];
  __shared__ float b1s[64], b2s[64], b3s[64], ab1s[64], aw2s[64];
  __shared__ float hb[8][8][GD];
  for (int i = threadIdx.x; i < 128 * 64; i += 512) w1s[i] = f2bf(W1[i]);
  for (int i = threadIdx.x; i < 64 * 64; i += 512) {
    w2s[i] = f2bf(W2[i]); w3s[i] = f2bf(W3[i]); was[i] = f2bf(aW1b[i]);
  }
  if (threadIdx.x < 64) {
    b1s[threadIdx.x] = b1[threadIdx.x]; b2s[threadIdx.x] = b2[threadIdx.x];
    b3s[threadIdx.x] = b3[threadIdx.x]; ab1s[threadIdx.x] = ab1[threadIdx.x];
    aw2s[threadIdx.x] = aW2[threadIdx.x];
  }
  __syncthreads();
  const int lane = threadIdx.x & 63, wave = threadIdx.x >> 6;
  const int M = GB * GN * GN;
  float ab2v = ab2[0];
  for (int base = blockIdx.x * 64; base < M; base += gridDim.x * 64) {
    int rb = base + wave * 8;
    const float* pa[8]; const float* pb[8];
#pragma unroll
    for (int r = 0; r < 8; r++) {
      int row = rb + r;
      pa[r] = E_i + (size_t)__builtin_amdgcn_readfirstlane(items[row]) * 64;
      pb[r] = E_r + (size_t)__builtin_amdgcn_readfirstlane(items_r[row]) * 64;
    }
    float acc[8];
    mlp3_rows<8>(lane, pa, pb, w1s, w2s, w3s, b1s, b2s, b3s, hb[wave], acc);
#pragma unroll
    for (int r = 0; r < 8; r++) hb[wave][r][lane] = acc[r];  // xoa rows
#pragma unroll
    for (int r = 0; r < 8; r++) {
      int row = rb + r;
      int b_ = row / (GN * GN), n2 = row % GN;
      float h = ab1s[lane] + poW[(size_t)(b_ * GN + n2) * 64 + lane];
#pragma unroll
      for (int kc = 0; kc < 16; kc++) {
        float4 x = *(const float4*)(&hb[wave][r][kc * 4]);
        h = fmaf(x.x, bf2f(was[(kc * 4 + 0) * 64 + lane]), h);
        h = fmaf(x.y, bf2f(was[(kc * 4 + 1) * 64 + lane]), h);
        h = fmaf(x.z, bf2f(was[(kc * 4 + 2) * 64 + lane]), h);
        h = fmaf(x.w, bf2f(was[(kc * 4 + 3) * 64 + lane]), h);
      }
      float v = fmaxf(h, 0.f) * aw2s[lane];
      v = wave_sum(v);
      if (lane == 0) sOut[row] = v + ab2v;
    }
  }
}

// ---------- pass 2: ho[b,n2] = relu( (sum_n1 alpha*xoa) @ linO + linO_b ) ----------
__global__ __launch_bounds__(512, 2) void k_xoa_pass2(
    const float* __restrict__ E_i, const float* __restrict__ E_r,
    const int* __restrict__ items, const int* __restrict__ items_r,
    const float* __restrict__ W1, const float* __restrict__ b1,
    const float* __restrict__ W2, const float* __restrict__ b2,
    const float* __restrict__ W3, const float* __restrict__ b3,
    const float* __restrict__ alpha,
    const float* __restrict__ linW, const float* __restrict__ linB,
    float* __restrict__ ho) {
  __shared__ unsigned short w1s[128 * 64], w2s[64 * 64], w3s[64 * 64], lws[64 * 64];
  __shared__ float b1s[64], b2s[64], b3s[64], lbs[64];
  __shared__ float hb[8][6][GD];
  for (int i = threadIdx.x; i < 128 * 64; i += 512) w1s[i] = f2bf(W1[i]);
  for (int i = threadIdx.x; i < 64 * 64; i += 512) {
    w2s[i] = f2bf(W2[i]); w3s[i] = f2bf(W3[i]); lws[i] = f2bf(linW[i]);
  }
  if (threadIdx.x < 64) {
    b1s[threadIdx.x] = b1[threadIdx.x]; b2s[threadIdx.x] = b2[threadIdx.x];
    b3s[threadIdx.x] = b3[threadIdx.x]; lbs[threadIdx.x] = linB[threadIdx.x];
  }
  __syncthreads();
  const int lane = threadIdx.x & 63, wave = threadIdx.x >> 6;
  int wid = blockIdx.x * 8 + wave;           // 0 .. B*N-1 (grid sized exactly)
  int b_ = wid / GN, n2 = wid % GN;
  float hacc = 0.f;
  for (int c = 0; c < 5; c++) {              // 5 chunks of 6 over n1
    const float* pa[6]; const float* pb[6]; float al[6];
#pragma unroll
    for (int r = 0; r < 6; r++) {
      int row = (b_ * GN + (c * 6 + r)) * GN + n2;
      pa[r] = E_i + (size_t)__builtin_amdgcn_readfirstlane(items[row]) * 64;
      pb[r] = E_r + (size_t)__builtin_amdgcn_readfirstlane(items_r[row]) * 64;
      al[r] = alpha[row];
    }
    float acc[6];
    mlp3_rows<6>(lane, pa, pb, w1s, w2s, w3s, b1s, b2s, b3s, hb[wave], acc);
#pragma unroll
    for (int r = 0; r < 6; r++) hacc = fmaf(al[r], acc[r], hacc);
  }
  hb[wave][0][lane] = hacc;
  float o = lbs[lane];
#pragma unroll
  for (int kc = 0; kc < 16; kc++) {
    float4 x = *(const float4*)(&hb[wave][0][kc * 4]);
    o = fmaf(x.x, bf2f(lws[(kc * 4 + 0) * 64 + lane]), o);
    o = fmaf(x.y, bf2f(lws[(kc * 4 + 1) * 64 + lane]), o);
    o = fmaf(x.z, bf2f(lws[(kc * 4 + 2) * 64 + lane]), o);
    o = fmaf(x.w, bf2f(lws[(kc * 4 + 3) * 64 + lane]), o);
  }
  ho[(size_t)wid * 64 + lane] = fmaxf(o, 0.f);
}

// ---------- final: gl[b] = mlp3(concat(hi,zj)) with 1-wide layers ----------
__global__ __launch_bounds__(256) void k_final(
    const float* __restrict__ hi, const float* __restrict__ zj,
    const float* __restrict__ gW1, const float* __restrict__ gb1,
    const float* __restrict__ gW2, const float* __restrict__ gb2,
    const float* __restrict__ gW3, const float* __restrict__ gb3,
    float* __restrict__ out) {
  const int lane = threadIdx.x & 63, wave = threadIdx.x >> 6;
  int b = blockIdx.x * 4 + wave;
  float v = hi[(size_t)b * 64 + lane] * gW1[lane] + zj[(size_t)b * 64 + lane] * gW1[64 + lane];
  v = wave_sum(v);
  if (lane == 0) {
    float h = fmaxf(v + gb1[0], 0.f);
    h = fmaxf(h * gW2[0] + gb2[0], 0.f);
    out[b] = h * gW3[0] + gb3[0];
  }
}

extern "C" void kernel_launch(void* const* d_in, const int* in_sizes, int n_in,
                              void* d_out, int out_size, void* d_ws, size_t ws_size,
                              hipStream_t stream) {
  const float* E_u = (const float*)d_in[0];
  const float* E_i = (const float*)d_in[1];
  const float* E_r = (const float*)d_in[2];
  const float* gvW1 = (const float*)d_in[3];  const float* gvb1 = (const float*)d_in[4];
  const float* gvW2 = (const float*)d_in[5];  const float* gvb2 = (const float*)d_in[6];
  const float* gvW3 = (const float*)d_in[7];  const float* gvb3 = (const float*)d_in[8];
  const float* umW1 = (const float*)d_in[9];  const float* umb1 = (const float*)d_in[10];
  const float* umW2 = (const float*)d_in[11]; const float* umb2 = (const float*)d_in[12];
  const float* umW3 = (const float*)d_in[13]; const float* umb3 = (const float*)d_in[14];
  const float* guW1 = (const float*)d_in[15]; const float* gub1 = (const float*)d_in[16];
  const float* guW2 = (const float*)d_in[17]; const float* gub2 = (const float*)d_in[18];
  const float* guW3 = (const float*)d_in[19]; const float* gub3 = (const float*)d_in[20];
  const float* aIW1 = (const float*)d_in[21]; const float* aIb1 = (const float*)d_in[22];
  const float* aIW2 = (const float*)d_in[23]; const float* aIb2 = (const float*)d_in[24];
  const float* aOW1 = (const float*)d_in[25]; const float* aOb1 = (const float*)d_in[26];
  const float* aOW2 = (const float*)d_in[27]; const float* aOb2 = (const float*)d_in[28];
  const float* aSW1 = (const float*)d_in[29]; const float* aSb1 = (const float*)d_in[30];
  const float* aSW2 = (const float*)d_in[31]; const float* aSb2 = (const float*)d_in[32];
  const float* aiW1 = (const float*)d_in[33]; const float* aib1 = (const float*)d_in[34];
  const float* aiW2 = (const float*)d_in[35]; const float* aib2 = (const float*)d_in[36];
  const float* linIW = (const float*)d_in[37]; const float* linIb = (const float*)d_in[38];
  const float* linOW = (const float*)d_in[39]; const float* linOb = (const float*)d_in[40];
  const float* ilinW = (const float*)d_in[41]; const float* ilinb = (const float*)d_in[42];
  const float* gW1 = (const float*)d_in[43]; const float* gb1 = (const float*)d_in[44];
  const float* gW2 = (const float*)d_in[45]; const float* gb2 = (const float*)d_in[46];
  const float* gW3 = (const float*)d_in[47]; const float* gb3 = (const float*)d_in[48];
  const int* nodes_u = (const int*)d_in[49];
  const int* nodes_i = (const int*)d_in[50];
  const int* u_items = (const int*)d_in[51];
  const int* u_users = (const int*)d_in[52];
  const int* i_users = (const int*)d_in[53];
  const int* u_items_r = (const int*)d_in[54];
  const int* uu_items = (const int*)d_in[55];
  const int* uu_items_r = (const int*)d_in[56];
  const int* i_users_r = (const int*)d_in[57];
  float* out = (float*)d_out;

  // workspace carve-up (fp32), ~18.7 MB total
  float* p = (float*)d_ws;
  float* piWI = p; p += GB * GD;
  float* piWS = p; p += GB * GD;
  float* qjWi = p; p += GB * GD;
  float* poW  = p; p += GB * GN * GD;
  float* xia  = p; p += GB * GN * GD;
  float* fjt  = p; p += GB * GN * GD;
  float* ho   = p; p += GB * GN * GD;
  float* sI   = p; p += GB * GN;
  float* sS   = p; p += GB * GN;
  float* si   = p; p += GB * GN;
  float* sO   = p; p += GB * GN * GN;
  float* hiI  = p; p += GB * GD;
  float* hiS  = p; p += GB * GD;
  float* hi   = p; p += GB * GD;
  float* zj   = p; p += GB * GD;

  const int BN = GB * GN;           // 15360
  // self-rep @ W1(top-half) precomputes
  k_rowlin<<<GB / 32, 256, 0, stream>>>(GB, E_u, nodes_u, aIW1, piWI);
  k_rowlin<<<GB / 32, 256, 0, stream>>>(GB, E_u, nodes_u, aSW1, piWS);
  k_rowlin<<<GB / 32, 256, 0, stream>>>(GB, E_i, nodes_i, aiW1, qjWi);
  k_rowlin<<<BN / 32, 256, 0, stream>>>(BN, E_u, u_users, aOW1, poW);

  // item-space aggregation
  k_mlp3<<<BN / 64, 512, 0, stream>>>(BN, E_i, u_items, E_r, u_items_r,
                                      gvW1, gvb1, gvW2, gvb2, gvW3, gvb3, xia);
  k_score<<<BN / 32, 256, 0, stream>>>(BN, piWI, xia, aIW1 + 64 * 64, aIb1, aIW2, aIb2, sI);
  k_softmax_col<<<GN, 256, 0, stream>>>(sI, GN);
  k_wsum_lin<<<GB, 64, 0, stream>>>(GN, sI, xia, linIW, linIb, hiI);

  // social-space aggregation (xoa computed twice, never materialized)
  k_xoa_pass1<<<1800, 512, 0, stream>>>(E_i, E_r, uu_items, uu_items_r,
                                        gvW1, gvb1, gvW2, gvb2, gvW3, gvb3,
                                        poW, aOW1 + 64 * 64, aOb1, aOW2, aOb2, sO);
  k_softmax_col<<<GN * GN, 256, 0, stream>>>(sO, GN * GN);
  k_xoa_pass2<<<BN / 8, 512, 0, stream>>>(E_i, E_r, uu_items, uu_items_r,
                                          gvW1, gvb1, gvW2, gvb2, gvW3, gvb3,
                                          sO, linOW, linOb, ho);
  k_score<<<BN / 32, 256, 0, stream>>>(BN, piWS, ho, aSW1 + 64 * 64, aSb1, aSW2, aSb2, sS);
  k_softmax_col<<<GN, 256, 0, stream>>>(sS, GN);
  k_wsum_lin<<<GB, 64, 0, stream>>>(GN, sS, ho, linOW, linOb, hiS);  // reuses linO per reference
  k_mlp3<<<GB / 64, 512, 0, stream>>>(GB, hiI, nullptr, hiS, nullptr,
                                      umW1, umb1, umW2, umb2, umW3, umb3, hi);

  // item modeling
  k_mlp3<<<BN / 64, 512, 0, stream>>>(BN, E_u, i_users, E_r, i_users_r,
                                      guW1, gub1, guW2, gub2, guW3, gub3, fjt);
  k_score<<<BN / 32, 256, 0, stream>>>(BN, qjWi, fjt, aiW1 + 64 * 64, aib1, aiW2, aib2, si);
  k_softmax_col<<<GN, 256, 0, stream>>>(si, GN);
  k_wsum_lin<<<GB, 64, 0, stream>>>(GN, si, fjt, ilinW, ilinb, zj);

  // rating prediction
  k_final<<<GB / 4, 256, 0, stream>>>(hi, zj, gW1, gb1, gW2, gb2, gW3, gb3, out);
}

// Round 2
// 856.093 us; speedup vs baseline: 1.6990x; 1.6990x over previous
//
#include <hip/hip_runtime.h>
#include <cstdint>
#include <cstddef>

// GraphRec forward. Heavy B*N*N row-MLPs on bf16 MFMA (16x16x32), small glue
// kernels remain fp32 vector.

#define GB 512   // batch
#define GN 30    // neighbors
#define GD 64    // feature dim

typedef unsigned short u16;
typedef __attribute__((ext_vector_type(8))) short short8v;  // 8 bf16 (4 VGPRs)
typedef __attribute__((ext_vector_type(4))) float f32x4;

// ---------- small helpers ----------
__device__ __forceinline__ u16 f2bf(float x) {
  union { float f; uint32_t u; } c; c.f = x;
  uint32_t r = c.u + 0x7fffu + ((c.u >> 16) & 1u);   // RTN-even
  return (u16)(r >> 16);
}
__device__ __forceinline__ float bf2f(u16 b) {
  union { float f; uint32_t u; } c; c.u = ((uint32_t)b) << 16; return c.f;
}
__device__ __forceinline__ float wave_sum(float v) {
#pragma unroll
  for (int off = 32; off >= 1; off >>= 1) v += __shfl_xor(v, off, 64);
  return v;
}

// ================= MFMA path =================
// LDS layouts: X rows padded to 136 u16 (272B) -> conflict-free ds_read_b128
// for A frags; weights transposed [n][k] padded to 136/72 u16 for B frags.
// Wave w owns rows w*16..w*16+15; layers are wave-private (no barriers).

__device__ __forceinline__ void mfma_3layers(
    int lane, int wave,
    const u16* xs, const u16* w1s, const u16* w2s, const u16* w3s,
    const float* b1s, const float* b2s, u16* hs, f32x4* c3) {
  const int m = lane & 15, quad = lane >> 4;
  const int row = wave * 16 + m;
  const f32x4 zz = {0.f, 0.f, 0.f, 0.f};
  f32x4 cc[4];
#pragma unroll
  for (int c = 0; c < 4; c++) cc[c] = zz;
#pragma unroll
  for (int kk = 0; kk < 4; kk++) {
    short8v av = *(const short8v*)(xs + row * 136 + kk * 32 + quad * 8);
#pragma unroll
    for (int c = 0; c < 4; c++) {
      short8v bv = *(const short8v*)(w1s + (c * 16 + m) * 136 + kk * 32 + quad * 8);
      cc[c] = __builtin_amdgcn_mfma_f32_16x16x32_bf16(av, bv, cc[c], 0, 0, 0);
    }
  }
#pragma unroll
  for (int c = 0; c < 4; c++)
#pragma unroll
    for (int r = 0; r < 4; r++) {
      int rr = wave * 16 + quad * 4 + r;
      hs[rr * 72 + c * 16 + m] = f2bf(fmaxf(cc[c][r] + b1s[c * 16 + m], 0.f));
    }
  // layer 2 (K=64)
#pragma unroll
  for (int c = 0; c < 4; c++) cc[c] = zz;
#pragma unroll
  for (int kk = 0; kk < 2; kk++) {
    short8v av = *(const short8v*)(hs + row * 72 + kk * 32 + quad * 8);
#pragma unroll
    for (int c = 0; c < 4; c++) {
      short8v bv = *(const short8v*)(w2s + (c * 16 + m) * 72 + kk * 32 + quad * 8);
      cc[c] = __builtin_amdgcn_mfma_f32_16x16x32_bf16(av, bv, cc[c], 0, 0, 0);
    }
  }
#pragma unroll
  for (int c = 0; c < 4; c++)
#pragma unroll
    for (int r = 0; r < 4; r++) {
      int rr = wave * 16 + quad * 4 + r;
      hs[rr * 72 + c * 16 + m] = f2bf(fmaxf(cc[c][r] + b2s[c * 16 + m], 0.f));
    }
  // layer 3 (K=64, bias added by caller)
#pragma unroll
  for (int c = 0; c < 4; c++) c3[c] = zz;
#pragma unroll
  for (int kk = 0; kk < 2; kk++) {
    short8v av = *(const short8v*)(hs + row * 72 + kk * 32 + quad * 8);
#pragma unroll
    for (int c = 0; c < 4; c++) {
      short8v bv = *(const short8v*)(w3s + (c * 16 + m) * 72 + kk * 32 + quad * 8);
      c3[c] = __builtin_amdgcn_mfma_f32_16x16x32_bf16(av, bv, c3[c], 0, 0, 0);
    }
  }
}

// transpose+convert weights once: dstT[n*K+k] = bf16(src[k*64+n])
__global__ void k_prep(const float* __restrict__ gvW1, const float* __restrict__ gvW2,
                       const float* __restrict__ gvW3, const float* __restrict__ aOW1,
                       const float* __restrict__ guW1, const float* __restrict__ guW2,
                       const float* __restrict__ guW3,
                       u16* gv1t, u16* gv2t, u16* gv3t, u16* aot,
                       u16* gu1t, u16* gu2t, u16* gu3t) {
  int i = blockIdx.x * 256 + threadIdx.x;   // 36864 total
  const float* src; u16* dst; int sh; int o = i;
  if (o < 8192)        { src = gvW1;           dst = gv1t; sh = 7; }
  else if (o < 12288)  { o -= 8192;  src = gvW2; dst = gv2t; sh = 6; }
  else if (o < 16384)  { o -= 12288; src = gvW3; dst = gv3t; sh = 6; }
  else if (o < 20480)  { o -= 16384; src = aOW1 + 64 * 64; dst = aot; sh = 6; }
  else if (o < 28672)  { o -= 20480; src = guW1; dst = gu1t; sh = 7; }
  else if (o < 32768)  { o -= 28672; src = guW2; dst = gu2t; sh = 6; }
  else                 { o -= 32768; src = guW3; dst = gu3t; sh = 6; }
  int n = o >> sh, k = o & ((1 << sh) - 1);
  dst[(size_t)n * (1 << sh) + k] = f2bf(src[(size_t)k * 64 + n]);
}

// generic MFMA MLP3 over M rows of concat(tabA[idxA], tabB[idxB]) -> out fp32
__global__ __launch_bounds__(256, 2) void k_mlp3_mfma(
    const float* __restrict__ tabA, const int* __restrict__ idxA,
    const float* __restrict__ tabB, const int* __restrict__ idxB,
    const u16* __restrict__ w1t, const u16* __restrict__ w2t, const u16* __restrict__ w3t,
    const float* __restrict__ b1, const float* __restrict__ b2, const float* __restrict__ b3,
    float* __restrict__ out) {
  __shared__ __align__(16) u16 xs[64 * 136], w1s[64 * 136], w2s[64 * 72], w3s[64 * 72], hs[64 * 72];
  __shared__ float b1s[64], b2s[64], b3s[64];
  int t = threadIdx.x;
  for (int i = t; i < 64 * 16; i += 256) { int n = i >> 4, j = i & 15;
    ((uint4*)(w1s + n * 136))[j] = ((const uint4*)(w1t + n * 128))[j]; }
  for (int i = t; i < 64 * 8; i += 256) { int n = i >> 3, j = i & 7;
    ((uint4*)(w2s + n * 72))[j] = ((const uint4*)(w2t + n * 64))[j];
    ((uint4*)(w3s + n * 72))[j] = ((const uint4*)(w3t + n * 64))[j]; }
  if (t < 64) { b1s[t] = b1[t]; b2s[t] = b2[t]; b3s[t] = b3[t]; }
  int base = blockIdx.x * 64;
  { int lr = t >> 2, q = t & 3; int row = base + lr;
    const float* src = (q < 2) ? (tabA + (size_t)idxA[row] * 64 + q * 32)
                               : (tabB + (size_t)idxB[row] * 64 + (q - 2) * 32);
    u16* dst = xs + lr * 136 + q * 32;
    const float4* s4 = (const float4*)src;
#pragma unroll
    for (int h = 0; h < 8; h++) { float4 v = s4[h]; ushort4 u;
      u.x = f2bf(v.x); u.y = f2bf(v.y); u.z = f2bf(v.z); u.w = f2bf(v.w);
      *(ushort4*)(dst + h * 4) = u; }
  }
  __syncthreads();
  int lane = t & 63, wave = t >> 6;
  f32x4 c3[4];
  mfma_3layers(lane, wave, xs, w1s, w2s, w3s, b1s, b2s, hs, c3);
  int m = lane & 15, quad = lane >> 4;
#pragma unroll
  for (int c = 0; c < 4; c++)
#pragma unroll
    for (int r = 0; r < 4; r++) {
      int rr = wave * 16 + quad * 4 + r;
      out[(size_t)(base + rr) * 64 + c * 16 + m] = c3[c][r] + b3s[c * 16 + m];
    }
}

// pass1: xoa rows + fused attO score -> sOut[B*N*N]
__global__ __launch_bounds__(256, 2) void k_xoa1_mfma(
    const float* __restrict__ E_i, const float* __restrict__ E_r,
    const int* __restrict__ items, const int* __restrict__ items_r,
    const u16* __restrict__ w1t, const u16* __restrict__ w2t, const u16* __restrict__ w3t,
    const float* __restrict__ b1, const float* __restrict__ b2, const float* __restrict__ b3,
    const u16* __restrict__ aot, const float* __restrict__ ab1,
    const float* __restrict__ aW2, const float* __restrict__ ab2,
    const float* __restrict__ poW, float* __restrict__ sOut) {
  __shared__ __align__(16) u16 xs[64 * 136], w1s[64 * 136], w2s[64 * 72], w3s[64 * 72], was[64 * 72], hs[64 * 72];
  __shared__ float b1s[64], b2s[64], b3s[64], ab1s[64], aw2s[64];
  int t = threadIdx.x;
  for (int i = t; i < 64 * 16; i += 256) { int n = i >> 4, j = i & 15;
    ((uint4*)(w1s + n * 136))[j] = ((const uint4*)(w1t + n * 128))[j]; }
  for (int i = t; i < 64 * 8; i += 256) { int n = i >> 3, j = i & 7;
    ((uint4*)(w2s + n * 72))[j] = ((const uint4*)(w2t + n * 64))[j];
    ((uint4*)(w3s + n * 72))[j] = ((const uint4*)(w3t + n * 64))[j];
    ((uint4*)(was + n * 72))[j] = ((const uint4*)(aot + n * 64))[j]; }
  if (t < 64) { b1s[t] = b1[t]; b2s[t] = b2[t]; b3s[t] = b3[t];
                ab1s[t] = ab1[t]; aw2s[t] = aW2[t]; }
  int base = blockIdx.x * 64;
  { int lr = t >> 2, q = t & 3; int row = base + lr;
    const float* src = (q < 2) ? (E_i + (size_t)items[row] * 64 + q * 32)
                               : (E_r + (size_t)items_r[row] * 64 + (q - 2) * 32);
    u16* dst = xs + lr * 136 + q * 32;
    const float4* s4 = (const float4*)src;
#pragma unroll
    for (int h = 0; h < 8; h++) { float4 v = s4[h]; ushort4 u;
      u.x = f2bf(v.x); u.y = f2bf(v.y); u.z = f2bf(v.z); u.w = f2bf(v.w);
      *(ushort4*)(dst + h * 4) = u; }
  }
  __syncthreads();
  int lane = t & 63, wave = t >> 6;
  f32x4 c3[4];
  mfma_3layers(lane, wave, xs, w1s, w2s, w3s, b1s, b2s, hs, c3);
  int m = lane & 15, quad = lane >> 4;
  const f32x4 zz = {0.f, 0.f, 0.f, 0.f};
  // xoa (with bias, no relu) -> hs, then att layer
#pragma unroll
  for (int c = 0; c < 4; c++)
#pragma unroll
    for (int r = 0; r < 4; r++) {
      int rr = wave * 16 + quad * 4 + r;
      hs[rr * 72 + c * 16 + m] = f2bf(c3[c][r] + b3s[c * 16 + m]);
    }
  f32x4 c4[4];
#pragma unroll
  for (int c = 0; c < 4; c++) c4[c] = zz;
  int row = wave * 16 + m;
#pragma unroll
  for (int kk = 0; kk < 2; kk++) {
    short8v av = *(const short8v*)(hs + row * 72 + kk * 32 + quad * 8);
#pragma unroll
    for (int c = 0; c < 4; c++) {
      short8v bv = *(const short8v*)(was + (c * 16 + m) * 72 + kk * 32 + quad * 8);
      c4[c] = __builtin_amdgcn_mfma_f32_16x16x32_bf16(av, bv, c4[c], 0, 0, 0);
    }
  }
  float ab2v = ab2[0];
  float part[4] = {0.f, 0.f, 0.f, 0.f};
#pragma unroll
  for (int r = 0; r < 4; r++) {
    int gRow = base + wave * 16 + quad * 4 + r;
    int b_ = gRow / (GN * GN);
    int n2 = gRow % GN;
    const float* pw = poW + ((size_t)b_ * GN + n2) * 64;
#pragma unroll
    for (int c = 0; c < 4; c++) {
      int col = c * 16 + m;
      float h = c4[c][r] + pw[col] + ab1s[col];
      part[r] += fmaxf(h, 0.f) * aw2s[col];
    }
  }
#pragma unroll
  for (int r = 0; r < 4; r++) {
    float v = part[r];
    v += __shfl_xor(v, 1, 64); v += __shfl_xor(v, 2, 64);
    v += __shfl_xor(v, 4, 64); v += __shfl_xor(v, 8, 64);
    if (m == 0) sOut[base + wave * 16 + quad * 4 + r] = v + ab2v;
  }
}

// pass2: recompute xoa, alpha-weighted sum over n1, @linO+relu -> ho[B*N][64]
// block bb handles 2 (b_,n2) groups x 32 n1-slots (30 real + 2 dummy)
__global__ __launch_bounds__(256, 2) void k_xoa2_mfma(
    const float* __restrict__ E_i, const float* __restrict__ E_r,
    const int* __restrict__ items, const int* __restrict__ items_r,
    const u16* __restrict__ w1t, const u16* __restrict__ w2t, const u16* __restrict__ w3t,
    const float* __restrict__ b1, const float* __restrict__ b2, const float* __restrict__ b3,
    const float* __restrict__ alpha, const float* __restrict__ linW,
    const float* __restrict__ linB, float* __restrict__ ho) {
  __shared__ __align__(16) u16 xs[64 * 136];   // fbuf overlays after layer1
  __shared__ __align__(16) u16 w1s[64 * 136], w2s[64 * 72], w3s[64 * 72], hs[64 * 72], lws[64 * 64];
  __shared__ float redb[2 * 64];
  __shared__ float b1s[64], b2s[64], b3s[64], lbs[64];
  float* fbuf = (float*)xs;                    // 64*65 floats fits in 64*136 u16
  int t = threadIdx.x;
  for (int i = t; i < 64 * 16; i += 256) { int n = i >> 4, j = i & 15;
    ((uint4*)(w1s + n * 136))[j] = ((const uint4*)(w1t + n * 128))[j]; }
  for (int i = t; i < 64 * 8; i += 256) { int n = i >> 3, j = i & 7;
    ((uint4*)(w2s + n * 72))[j] = ((const uint4*)(w2t + n * 64))[j];
    ((uint4*)(w3s + n * 72))[j] = ((const uint4*)(w3t + n * 64))[j]; }
  for (int i = t; i < 4096; i += 256) lws[i] = f2bf(linW[i]);
  if (t < 64) { b1s[t] = b1[t]; b2s[t] = b2[t]; b3s[t] = b3[t]; lbs[t] = linB[t]; }
  int bb = blockIdx.x;
  { int lr = t >> 2, q = t & 3;
    int g = lr >> 5, n1 = lr & 31; if (n1 > 29) n1 = 29;
    int gid = bb * 2 + g, b_ = gid / GN, n2 = gid - b_ * GN;
    int drow = (b_ * GN + n1) * GN + n2;
    const float* src = (q < 2) ? (E_i + (size_t)items[drow] * 64 + q * 32)
                               : (E_r + (size_t)items_r[drow] * 64 + (q - 2) * 32);
    u16* dst = xs + lr * 136 + q * 32;
    const float4* s4 = (const float4*)src;
#pragma unroll
    for (int h = 0; h < 8; h++) { float4 v = s4[h]; ushort4 u;
      u.x = f2bf(v.x); u.y = f2bf(v.y); u.z = f2bf(v.z); u.w = f2bf(v.w);
      *(ushort4*)(dst + h * 4) = u; }
  }
  __syncthreads();
  int lane = t & 63, wave = t >> 6;
  f32x4 c3[4];
  mfma_3layers(lane, wave, xs, w1s, w2s, w3s, b1s, b2s, hs, c3);
  __syncthreads();   // all waves done reading xs before fbuf overlay writes
  int m = lane & 15, quad = lane >> 4;
#pragma unroll
  for (int c = 0; c < 4; c++)
#pragma unroll
    for (int r = 0; r < 4; r++) {
      int lr2 = wave * 16 + quad * 4 + r;
      int n1 = lr2 & 31, g = lr2 >> 5;
      int gid = bb * 2 + g, b_ = gid / GN, n2 = gid - b_ * GN;
      float al = (n1 < GN) ? alpha[(size_t)(b_ * GN + n1) * GN + n2] : 0.f;
      fbuf[lr2 * 65 + c * 16 + m] = (c3[c][r] + b3s[c * 16 + m]) * al;
    }
  __syncthreads();
  if (t < 128) {
    int g = t >> 6, col = t & 63;
    float s = 0.f;
#pragma unroll 8
    for (int i = 0; i < 32; i++) s += fbuf[(g * 32 + i) * 65 + col];
    redb[g * 64 + col] = s;
  }
  __syncthreads();
  if (t < 128) {
    int g = t >> 6, col = t & 63;
    int gid = bb * 2 + g;
    float acc = lbs[col];
#pragma unroll 8
    for (int k = 0; k < 64; k++) acc = fmaf(redb[g * 64 + k], bf2f(lws[k * 64 + col]), acc);
    ho[(size_t)gid * 64 + col] = fmaxf(acc, 0.f);
  }
}

// ================= vector glue kernels (unchanged from round 1) =================
template <int R>
__device__ __forceinline__ void mlp3_rows(
    int lane, const float* const* pa, const float* const* pb,
    const u16* w1s, const u16* w2s, const u16* w3s,
    const float* b1s, const float* b2s, const float* b3s,
    float (*hbw)[GD], float* acc) {
#pragma unroll
  for (int r = 0; r < R; r++) acc[r] = b1s[lane];
#pragma unroll 8
  for (int k = 0; k < 64; k++) {
    float w = bf2f(w1s[k * 64 + lane]);
#pragma unroll
    for (int r = 0; r < R; r++) acc[r] = fmaf(pa[r][k], w, acc[r]);
  }
#pragma unroll 8
  for (int k = 0; k < 64; k++) {
    float w = bf2f(w1s[(64 + k) * 64 + lane]);
#pragma unroll
    for (int r = 0; r < R; r++) acc[r] = fmaf(pb[r][k], w, acc[r]);
  }
#pragma unroll
  for (int r = 0; r < R; r++) hbw[r][lane] = fmaxf(acc[r], 0.f);
#pragma unroll
  for (int r = 0; r < R; r++) acc[r] = b2s[lane];
#pragma unroll
  for (int kc = 0; kc < 16; kc++) {
    float w0 = bf2f(w2s[(kc * 4 + 0) * 64 + lane]);
    float w1 = bf2f(w2s[(kc * 4 + 1) * 64 + lane]);
    float w2 = bf2f(w2s[(kc * 4 + 2) * 64 + lane]);
    float w3 = bf2f(w2s[(kc * 4 + 3) * 64 + lane]);
#pragma unroll
    for (int r = 0; r < R; r++) {
      float4 x = *(const float4*)(&hbw[r][kc * 4]);
      acc[r] = fmaf(x.x, w0, fmaf(x.y, w1, fmaf(x.z, w2, fmaf(x.w, w3, acc[r]))));
    }
  }
#pragma unroll
  for (int r = 0; r < R; r++) hbw[r][lane] = fmaxf(acc[r], 0.f);
#pragma unroll
  for (int r = 0; r < R; r++) acc[r] = b3s[lane];
#pragma unroll
  for (int kc = 0; kc < 16; kc++) {
    float w0 = bf2f(w3s[(kc * 4 + 0) * 64 + lane]);
    float w1 = bf2f(w3s[(kc * 4 + 1) * 64 + lane]);
    float w2 = bf2f(w3s[(kc * 4 + 2) * 64 + lane]);
    float w3 = bf2f(w3s[(kc * 4 + 3) * 64 + lane]);
#pragma unroll
    for (int r = 0; r < R; r++) {
      float4 x = *(const float4*)(&hbw[r][kc * 4]);
      acc[r] = fmaf(x.x, w0, fmaf(x.y, w1, fmaf(x.z, w2, fmaf(x.w, w3, acc[r]))));
    }
  }
}

__global__ __launch_bounds__(256, 4) void k_rowlin(
    int M, const float* __restrict__ tab, const int* __restrict__ idx,
    const float* __restrict__ W, float* __restrict__ out) {
  __shared__ float ws[64 * 64];
  for (int i = threadIdx.x; i < 64 * 64; i += 256) ws[i] = W[i];
  __syncthreads();
  const int lane = threadIdx.x & 63, wave = threadIdx.x >> 6;
  int base0 = (blockIdx.x * 4 + wave) * 8;
  if (base0 >= M) return;
  const float* p[8];
#pragma unroll
  for (int r = 0; r < 8; r++) {
    int ia = __builtin_amdgcn_readfirstlane(idx[base0 + r]);
    p[r] = tab + (size_t)ia * 64;
  }
  float acc[8];
#pragma unroll
  for (int r = 0; r < 8; r++) acc[r] = 0.f;
#pragma unroll 8
  for (int k = 0; k < 64; k++) {
    float w = ws[k * 64 + lane];
#pragma unroll
    for (int r = 0; r < 8; r++) acc[r] = fmaf(p[r][k], w, acc[r]);
  }
#pragma unroll
  for (int r = 0; r < 8; r++) out[(size_t)(base0 + r) * 64 + lane] = acc[r];
}

__global__ __launch_bounds__(512, 2) void k_mlp3(
    int M,
    const float* __restrict__ tabA, const int* __restrict__ idxA,
    const float* __restrict__ tabB, const int* __restrict__ idxB,
    const float* __restrict__ W1, const float* __restrict__ b1,
    const float* __restrict__ W2, const float* __restrict__ b2,
    const float* __restrict__ W3, const float* __restrict__ b3,
    float* __restrict__ out) {
  __shared__ u16 w1s[128 * 64], w2s[64 * 64], w3s[64 * 64];
  __shared__ float b1s[64], b2s[64], b3s[64];
  __shared__ float hb[8][8][GD];
  for (int i = threadIdx.x; i < 128 * 64; i += 512) w1s[i] = f2bf(W1[i]);
  for (int i = threadIdx.x; i < 64 * 64; i += 512) { w2s[i] = f2bf(W2[i]); w3s[i] = f2bf(W3[i]); }
  if (threadIdx.x < 64) { b1s[threadIdx.x] = b1[threadIdx.x]; b2s[threadIdx.x] = b2[threadIdx.x]; b3s[threadIdx.x] = b3[threadIdx.x]; }
  __syncthreads();
  const int lane = threadIdx.x & 63, wave = threadIdx.x >> 6;
  for (int base = blockIdx.x * 64; base < M; base += gridDim.x * 64) {
    int rb = base + wave * 8;
    const float* pa[8]; const float* pb[8];
#pragma unroll
    for (int r = 0; r < 8; r++) {
      int row = rb + r;
      int ia = idxA ? idxA[row] : row;
      pa[r] = tabA + (size_t)__builtin_amdgcn_readfirstlane(ia) * 64;
      int ib = idxB ? idxB[row] : row;
      pb[r] = tabB + (size_t)__builtin_amdgcn_readfirstlane(ib) * 64;
    }
    float acc[8];
    mlp3_rows<8>(lane, pa, pb, w1s, w2s, w3s, b1s, b2s, b3s, hb[wave], acc);
#pragma unroll
    for (int r = 0; r < 8; r++) out[(size_t)(rb + r) * 64 + lane] = acc[r];
  }
}

__global__ __launch_bounds__(256, 4) void k_score(
    int M, const float* __restrict__ selfW, const float* __restrict__ X,
    const float* __restrict__ W1b, const float* __restrict__ b1,
    const float* __restrict__ W2, const float* __restrict__ b2,
    float* __restrict__ sOut) {
  __shared__ float ws[64 * 64];
  __shared__ float w2s[64], b1s[64];
  for (int i = threadIdx.x; i < 64 * 64; i += 256) ws[i] = W1b[i];
  if (threadIdx.x < 64) { w2s[threadIdx.x] = W2[threadIdx.x]; b1s[threadIdx.x] = b1[threadIdx.x]; }
  __syncthreads();
  const int lane = threadIdx.x & 63, wave = threadIdx.x >> 6;
  int rb = (blockIdx.x * 4 + wave) * 8;
  if (rb >= M) return;
  const float* px[8]; float acc[8];
#pragma unroll
  for (int r = 0; r < 8; r++) {
    int row = rb + r;
    px[r] = X + (size_t)row * 64;
    acc[r] = b1s[lane] + selfW[(size_t)(row / GN) * 64 + lane];
  }
#pragma unroll 8
  for (int k = 0; k < 64; k++) {
    float w = ws[k * 64 + lane];
#pragma unroll
    for (int r = 0; r < 8; r++) acc[r] = fmaf(px[r][k], w, acc[r]);
  }
  float bb2 = b2[0];
#pragma unroll
  for (int r = 0; r < 8; r++) {
    float v = fmaxf(acc[r], 0.f) * w2s[lane];
    v = wave_sum(v);
    if (lane == 0) sOut[rb + r] = v + bb2;
  }
}

__global__ __launch_bounds__(256) void k_softmax_col(float* __restrict__ s, int C) {
  int c = blockIdx.x, t = threadIdx.x;
  int lane = t & 63, wave = t >> 6;
  float v0 = s[(size_t)t * C + c];
  float v1 = s[(size_t)(t + 256) * C + c];
  float m = fmaxf(v0, v1);
#pragma unroll
  for (int off = 32; off >= 1; off >>= 1) m = fmaxf(m, __shfl_xor(m, off, 64));
  __shared__ float rm[4], rs[4];
  if (lane == 0) rm[wave] = m;
  __syncthreads();
  float M4 = fmaxf(fmaxf(rm[0], rm[1]), fmaxf(rm[2], rm[3]));
  float e0 = expf(v0 - M4), e1 = expf(v1 - M4);
  float sm = wave_sum(e0 + e1);
  if (lane == 0) rs[wave] = sm;
  __syncthreads();
  float inv = 1.f / (rs[0] + rs[1] + rs[2] + rs[3]);
  s[(size_t)t * C + c] = e0 * inv;
  s[(size_t)(t + 256) * C + c] = e1 * inv;
}

__global__ __launch_bounds__(64) void k_wsum_lin(
    int C, const float* __restrict__ alpha, const float* __restrict__ X,
    const float* __restrict__ W, const float* __restrict__ bias,
    float* __restrict__ out) {
  int b = blockIdx.x, l = threadIdx.x;
  float t = 0.f;
  for (int n = 0; n < C; n++) t = fmaf(alpha[b * C + n], X[((size_t)b * C + n) * 64 + l], t);
  __shared__ float ts[64];
  ts[l] = t;
  float acc = bias[l];
#pragma unroll 8
  for (int k = 0; k < 64; k++) acc = fmaf(ts[k], W[k * 64 + l], acc);
  out[(size_t)b * 64 + l] = fmaxf(acc, 0.f);
}

__global__ __launch_bounds__(256) void k_final(
    const float* __restrict__ hi, const float* __restrict__ zj,
    const float* __restrict__ gW1, const float* __restrict__ gb1,
    const float* __restrict__ gW2, const float* __restrict__ gb2,
    const float* __restrict__ gW3, const float* __restrict__ gb3,
    float* __restrict__ out) {
  const int lane = threadIdx.x & 63, wave = threadIdx.x >> 6;
  int b = blockIdx.x * 4 + wave;
  float v = hi[(size_t)b * 64 + lane] * gW1[lane] + zj[(size_t)b * 64 + lane] * gW1[64 + lane];
  v = wave_sum(v);
  if (lane == 0) {
    float h = fmaxf(v + gb1[0], 0.f);
    h = fmaxf(h * gW2[0] + gb2[0], 0.f);
    out[b] = h * gW3[0] + gb3[0];
  }
}

extern "C" void kernel_launch(void* const* d_in, const int* in_sizes, int n_in,
                              void* d_out, int out_size, void* d_ws, size_t ws_size,
                              hipStream_t stream) {
  const float* E_u = (const float*)d_in[0];
  const float* E_i = (const float*)d_in[1];
  const float* E_r = (const float*)d_in[2];
  const float* gvW1 = (const float*)d_in[3];  const float* gvb1 = (const float*)d_in[4];
  const float* gvW2 = (const float*)d_in[5];  const float* gvb2 = (const float*)d_in[6];
  const float* gvW3 = (const float*)d_in[7];  const float* gvb3 = (const float*)d_in[8];
  const float* umW1 = (const float*)d_in[9];  const float* umb1 = (const float*)d_in[10];
  const float* umW2 = (const float*)d_in[11]; const float* umb2 = (const float*)d_in[12];
  const float* umW3 = (const float*)d_in[13]; const float* umb3 = (const float*)d_in[14];
  const float* guW1 = (const float*)d_in[15]; const float* gub1 = (const float*)d_in[16];
  const float* guW2 = (const float*)d_in[17]; const float* gub2 = (const float*)d_in[18];
  const float* guW3 = (const float*)d_in[19]; const float* gub3 = (const float*)d_in[20];
  const float* aIW1 = (const float*)d_in[21]; const float* aIb1 = (const float*)d_in[22];
  const float* aIW2 = (const float*)d_in[23]; const float* aIb2 = (const float*)d_in[24];
  const float* aOW1 = (const float*)d_in[25]; const float* aOb1 = (const float*)d_in[26];
  const float* aOW2 = (const float*)d_in[27]; const float* aOb2 = (const float*)d_in[28];
  const float* aSW1 = (const float*)d_in[29]; const float* aSb1 = (const float*)d_in[30];
  const float* aSW2 = (const float*)d_in[31]; const float* aSb2 = (const float*)d_in[32];
  const float* aiW1 = (const float*)d_in[33]; const float* aib1 = (const float*)d_in[34];
  const float* aiW2 = (const float*)d_in[35]; const float* aib2 = (const float*)d_in[36];
  const float* linIW = (const float*)d_in[37]; const float* linIb = (const float*)d_in[38];
  const float* linOW = (const float*)d_in[39]; const float* linOb = (const float*)d_in[40];
  const float* ilinW = (const float*)d_in[41]; const float* ilinb = (const float*)d_in[42];
  const float* gW1 = (const float*)d_in[43]; const float* gb1 = (const float*)d_in[44];
  const float* gW2 = (const float*)d_in[45]; const float* gb2 = (const float*)d_in[46];
  const float* gW3 = (const float*)d_in[47]; const float* gb3 = (const float*)d_in[48];
  const int* nodes_u = (const int*)d_in[49];
  const int* nodes_i = (const int*)d_in[50];
  const int* u_items = (const int*)d_in[51];
  const int* u_users = (const int*)d_in[52];
  const int* i_users = (const int*)d_in[53];
  const int* u_items_r = (const int*)d_in[54];
  const int* uu_items = (const int*)d_in[55];
  const int* uu_items_r = (const int*)d_in[56];
  const int* i_users_r = (const int*)d_in[57];
  float* out = (float*)d_out;

  // workspace carve-up
  float* p = (float*)d_ws;
  float* piWI = p; p += GB * GD;
  float* piWS = p; p += GB * GD;
  float* qjWi = p; p += GB * GD;
  float* poW  = p; p += GB * GN * GD;
  float* xia  = p; p += GB * GN * GD;
  float* fjt  = p; p += GB * GN * GD;
  float* ho   = p; p += GB * GN * GD;
  float* sI   = p; p += GB * GN;
  float* sS   = p; p += GB * GN;
  float* si   = p; p += GB * GN;
  float* sO   = p; p += GB * GN * GN;
  float* hiI  = p; p += GB * GD;
  float* hiS  = p; p += GB * GD;
  float* hi   = p; p += GB * GD;
  float* zj   = p; p += GB * GD;
  u16* q16 = (u16*)p;
  u16* gv1t = q16; q16 += 8192;
  u16* gv2t = q16; q16 += 4096;
  u16* gv3t = q16; q16 += 4096;
  u16* aot  = q16; q16 += 4096;
  u16* gu1t = q16; q16 += 8192;
  u16* gu2t = q16; q16 += 4096;
  u16* gu3t = q16; q16 += 4096;

  const int BN = GB * GN;           // 15360
  const int M2 = GB * GN * GN;      // 460800

  k_prep<<<144, 256, 0, stream>>>(gvW1, gvW2, gvW3, aOW1, guW1, guW2, guW3,
                                  gv1t, gv2t, gv3t, aot, gu1t, gu2t, gu3t);
  k_rowlin<<<GB / 32, 256, 0, stream>>>(GB, E_u, nodes_u, aIW1, piWI);
  k_rowlin<<<GB / 32, 256, 0, stream>>>(GB, E_u, nodes_u, aSW1, piWS);
  k_rowlin<<<GB / 32, 256, 0, stream>>>(GB, E_i, nodes_i, aiW1, qjWi);
  k_rowlin<<<BN / 32, 256, 0, stream>>>(BN, E_u, u_users, aOW1, poW);

  // item-space aggregation
  k_mlp3_mfma<<<BN / 64, 256, 0, stream>>>(E_i, u_items, E_r, u_items_r,
                                           gv1t, gv2t, gv3t, gvb1, gvb2, gvb3, xia);
  k_score<<<BN / 32, 256, 0, stream>>>(BN, piWI, xia, aIW1 + 64 * 64, aIb1, aIW2, aIb2, sI);
  k_softmax_col<<<GN, 256, 0, stream>>>(sI, GN);
  k_wsum_lin<<<GB, 64, 0, stream>>>(GN, sI, xia, linIW, linIb, hiI);

  // social-space aggregation
  k_xoa1_mfma<<<M2 / 64, 256, 0, stream>>>(E_i, E_r, uu_items, uu_items_r,
                                           gv1t, gv2t, gv3t, gvb1, gvb2, gvb3,
                                           aot, aOb1, aOW2, aOb2, poW, sO);
  k_softmax_col<<<GN * GN, 256, 0, stream>>>(sO, GN * GN);
  k_xoa2_mfma<<<BN / 2, 256, 0, stream>>>(E_i, E_r, uu_items, uu_items_r,
                                          gv1t, gv2t, gv3t, gvb1, gvb2, gvb3,
                                          sO, linOW, linOb, ho);
  k_score<<<BN / 32, 256, 0, stream>>>(BN, piWS, ho, aSW1 + 64 * 64, aSb1, aSW2, aSb2, sS);
  k_softmax_col<<<GN, 256, 0, stream>>>(sS, GN);
  k_wsum_lin<<<GB, 64, 0, stream>>>(GN, sS, ho, linOW, linOb, hiS);
  k_mlp3<<<GB / 64, 512, 0, stream>>>(GB, hiI, nullptr, hiS, nullptr,
                                      umW1, umb1, umW2, umb2, umW3, umb3, hi);

  // item modeling
  k_mlp3_mfma<<<BN / 64, 256, 0, stream>>>(E_u, i_users, E_r, i_users_r,
                                           gu1t, gu2t, gu3t, gub1, gub2, gub3, fjt);
  k_score<<<BN / 32, 256, 0, stream>>>(BN, qjWi, fjt, aiW1 + 64 * 64, aib1, aiW2, aib2, si);
  k_softmax_col<<<GN, 256, 0, stream>>>(si, GN);
  k_wsum_lin<<<GB, 64, 0, stream>>>(GN, si, fjt, ilinW, ilinb, zj);

  k_final<<<GB / 4, 256, 0, stream>>>(hi, zj, gW1, gb1, gW2, gb2, gW3, gb3, out);
}

// Round 3
// 722.376 us; speedup vs baseline: 2.0135x; 1.1851x over previous
//
#include <hip/hip_runtime.h>
#include <cstdint>
#include <cstddef>

// GraphRec forward. Heavy B*N*N row-MLP runs ONCE (persistent MFMA kernel,
// bf16 xoa materialized to workspace); pass2 is a cheap weighted reduction.

#define GB 512   // batch
#define GN 30    // neighbors
#define GD 64    // feature dim

typedef unsigned short u16;
typedef __attribute__((ext_vector_type(8))) short short8v;  // 8 bf16 (4 VGPRs)
typedef __attribute__((ext_vector_type(4))) float f32x4;

// ---------- small helpers ----------
__device__ __forceinline__ u16 f2bf(float x) {
  union { float f; uint32_t u; } c; c.f = x;
  uint32_t r = c.u + 0x7fffu + ((c.u >> 16) & 1u);   // RTN-even
  return (u16)(r >> 16);
}
__device__ __forceinline__ float bf2f(u16 b) {
  union { float f; uint32_t u; } c; c.u = ((uint32_t)b) << 16; return c.f;
}
__device__ __forceinline__ float wave_sum(float v) {
#pragma unroll
  for (int off = 32; off >= 1; off >>= 1) v += __shfl_xor(v, off, 64);
  return v;
}

// ================= MFMA path =================
// LDS layouts: X rows padded to 136 u16 -> conflict-free ds_read_b128 A frags;
// weights transposed [n][k] padded to 136/72 u16 for B frags.
// Wave w owns rows w*16..w*16+15 of xs/hs (staging thread->row mapping is
// wave-private), so the tile loop needs no __syncthreads().

__device__ __forceinline__ void mfma_3layers(
    int lane, int wave,
    const u16* xs, const u16* w1s, const u16* w2s, const u16* w3s,
    const float* b1s, const float* b2s, u16* hs, f32x4* c3) {
  const int m = lane & 15, quad = lane >> 4;
  const int row = wave * 16 + m;
  const f32x4 zz = {0.f, 0.f, 0.f, 0.f};
  f32x4 cc[4];
#pragma unroll
  for (int c = 0; c < 4; c++) cc[c] = zz;
#pragma unroll
  for (int kk = 0; kk < 4; kk++) {
    short8v av = *(const short8v*)(xs + row * 136 + kk * 32 + quad * 8);
#pragma unroll
    for (int c = 0; c < 4; c++) {
      short8v bv = *(const short8v*)(w1s + (c * 16 + m) * 136 + kk * 32 + quad * 8);
      cc[c] = __builtin_amdgcn_mfma_f32_16x16x32_bf16(av, bv, cc[c], 0, 0, 0);
    }
  }
#pragma unroll
  for (int c = 0; c < 4; c++)
#pragma unroll
    for (int r = 0; r < 4; r++) {
      int rr = wave * 16 + quad * 4 + r;
      hs[rr * 72 + c * 16 + m] = f2bf(fmaxf(cc[c][r] + b1s[c * 16 + m], 0.f));
    }
  // layer 2 (K=64)
#pragma unroll
  for (int c = 0; c < 4; c++) cc[c] = zz;
#pragma unroll
  for (int kk = 0; kk < 2; kk++) {
    short8v av = *(const short8v*)(hs + row * 72 + kk * 32 + quad * 8);
#pragma unroll
    for (int c = 0; c < 4; c++) {
      short8v bv = *(const short8v*)(w2s + (c * 16 + m) * 72 + kk * 32 + quad * 8);
      cc[c] = __builtin_amdgcn_mfma_f32_16x16x32_bf16(av, bv, cc[c], 0, 0, 0);
    }
  }
#pragma unroll
  for (int c = 0; c < 4; c++)
#pragma unroll
    for (int r = 0; r < 4; r++) {
      int rr = wave * 16 + quad * 4 + r;
      hs[rr * 72 + c * 16 + m] = f2bf(fmaxf(cc[c][r] + b2s[c * 16 + m], 0.f));
    }
  // layer 3 (K=64, bias added by caller)
#pragma unroll
  for (int c = 0; c < 4; c++) c3[c] = zz;
#pragma unroll
  for (int kk = 0; kk < 2; kk++) {
    short8v av = *(const short8v*)(hs + row * 72 + kk * 32 + quad * 8);
#pragma unroll
    for (int c = 0; c < 4; c++) {
      short8v bv = *(const short8v*)(w3s + (c * 16 + m) * 72 + kk * 32 + quad * 8);
      c3[c] = __builtin_amdgcn_mfma_f32_16x16x32_bf16(av, bv, c3[c], 0, 0, 0);
    }
  }
}

// transpose+convert weights once: dstT[n*K+k] = bf16(src[k*64+n])
__global__ void k_prep(const float* __restrict__ gvW1, const float* __restrict__ gvW2,
                       const float* __restrict__ gvW3, const float* __restrict__ aOW1,
                       const float* __restrict__ guW1, const float* __restrict__ guW2,
                       const float* __restrict__ guW3,
                       u16* gv1t, u16* gv2t, u16* gv3t, u16* aot,
                       u16* gu1t, u16* gu2t, u16* gu3t) {
  int i = blockIdx.x * 256 + threadIdx.x;   // 36864 total
  const float* src; u16* dst; int sh; int o = i;
  if (o < 8192)        { src = gvW1;           dst = gv1t; sh = 7; }
  else if (o < 12288)  { o -= 8192;  src = gvW2; dst = gv2t; sh = 6; }
  else if (o < 16384)  { o -= 12288; src = gvW3; dst = gv3t; sh = 6; }
  else if (o < 20480)  { o -= 16384; src = aOW1 + 64 * 64; dst = aot; sh = 6; }
  else if (o < 28672)  { o -= 20480; src = guW1; dst = gu1t; sh = 7; }
  else if (o < 32768)  { o -= 28672; src = guW2; dst = gu2t; sh = 6; }
  else                 { o -= 32768; src = guW3; dst = gu3t; sh = 6; }
  int n = o >> sh, k = o & ((1 << sh) - 1);
  dst[(size_t)n * (1 << sh) + k] = f2bf(src[(size_t)k * 64 + n]);
}

// generic MFMA MLP3 over M rows of concat(tabA[idxA], tabB[idxB]) -> out fp32
__global__ __launch_bounds__(256, 2) void k_mlp3_mfma(
    const float* __restrict__ tabA, const int* __restrict__ idxA,
    const float* __restrict__ tabB, const int* __restrict__ idxB,
    const u16* __restrict__ w1t, const u16* __restrict__ w2t, const u16* __restrict__ w3t,
    const float* __restrict__ b1, const float* __restrict__ b2, const float* __restrict__ b3,
    float* __restrict__ out) {
  __shared__ __align__(16) u16 xs[64 * 136], w1s[64 * 136], w2s[64 * 72], w3s[64 * 72], hs[64 * 72];
  __shared__ float b1s[64], b2s[64], b3s[64];
  int t = threadIdx.x;
  for (int i = t; i < 64 * 16; i += 256) { int n = i >> 4, j = i & 15;
    ((uint4*)(w1s + n * 136))[j] = ((const uint4*)(w1t + n * 128))[j]; }
  for (int i = t; i < 64 * 8; i += 256) { int n = i >> 3, j = i & 7;
    ((uint4*)(w2s + n * 72))[j] = ((const uint4*)(w2t + n * 64))[j];
    ((uint4*)(w3s + n * 72))[j] = ((const uint4*)(w3t + n * 64))[j]; }
  if (t < 64) { b1s[t] = b1[t]; b2s[t] = b2[t]; b3s[t] = b3[t]; }
  int base = blockIdx.x * 64;
  { int lr = t >> 2, q = t & 3; int row = base + lr;
    const float* src = (q < 2) ? (tabA + (size_t)idxA[row] * 64 + q * 32)
                               : (tabB + (size_t)idxB[row] * 64 + (q - 2) * 32);
    u16* dst = xs + lr * 136 + q * 32;
    const float4* s4 = (const float4*)src;
#pragma unroll
    for (int h = 0; h < 8; h++) { float4 v = s4[h]; ushort4 u;
      u.x = f2bf(v.x); u.y = f2bf(v.y); u.z = f2bf(v.z); u.w = f2bf(v.w);
      *(ushort4*)(dst + h * 4) = u; }
  }
  __syncthreads();
  int lane = t & 63, wave = t >> 6;
  f32x4 c3[4];
  mfma_3layers(lane, wave, xs, w1s, w2s, w3s, b1s, b2s, hs, c3);
  int m = lane & 15, quad = lane >> 4;
#pragma unroll
  for (int c = 0; c < 4; c++)
#pragma unroll
    for (int r = 0; r < 4; r++) {
      int rr = wave * 16 + quad * 4 + r;
      out[(size_t)(base + rr) * 64 + c * 16 + m] = c3[c][r] + b3s[c * 16 + m];
    }
}

// persistent pass1: xoa rows (bf16 -> global) + fused attO score -> sOut[B*N*N]
__global__ __launch_bounds__(256, 2) void k_xoa1_mfma(
    const float* __restrict__ E_i, const float* __restrict__ E_r,
    const int* __restrict__ items, const int* __restrict__ items_r,
    const u16* __restrict__ w1t, const u16* __restrict__ w2t, const u16* __restrict__ w3t,
    const float* __restrict__ b1, const float* __restrict__ b2, const float* __restrict__ b3,
    const u16* __restrict__ aot, const float* __restrict__ ab1,
    const float* __restrict__ aW2, const float* __restrict__ ab2,
    const float* __restrict__ poW, u16* __restrict__ xoa_bf,
    float* __restrict__ sOut) {
  __shared__ __align__(16) u16 xs[64 * 136], w1s[64 * 136], w2s[64 * 72], w3s[64 * 72], was[64 * 72], hs[64 * 72];
  __shared__ float b1s[64], b2s[64], b3s[64], ab1s[64], aw2s[64];
  int t = threadIdx.x;
  for (int i = t; i < 64 * 16; i += 256) { int n = i >> 4, j = i & 15;
    ((uint4*)(w1s + n * 136))[j] = ((const uint4*)(w1t + n * 128))[j]; }
  for (int i = t; i < 64 * 8; i += 256) { int n = i >> 3, j = i & 7;
    ((uint4*)(w2s + n * 72))[j] = ((const uint4*)(w2t + n * 64))[j];
    ((uint4*)(w3s + n * 72))[j] = ((const uint4*)(w3t + n * 64))[j];
    ((uint4*)(was + n * 72))[j] = ((const uint4*)(aot + n * 64))[j]; }
  if (t < 64) { b1s[t] = b1[t]; b2s[t] = b2[t]; b3s[t] = b3[t];
                ab1s[t] = ab1[t]; aw2s[t] = aW2[t]; }
  __syncthreads();   // weights ready; everything below is wave-private
  const int lane = t & 63, wave = t >> 6;
  const int m = lane & 15, quad = lane >> 4;
  const int lr = t >> 2, q = t & 3;      // staging row/quarter (rows 16w..16w+15)
  const float ab2v = ab2[0];
  const f32x4 zz = {0.f, 0.f, 0.f, 0.f};
  for (int tile = blockIdx.x; tile < (GB * GN * GN) / 64; tile += gridDim.x) {
    int base = tile * 64;
    { int row = base + lr;
      const float* src = (q < 2) ? (E_i + (size_t)items[row] * 64 + q * 32)
                                 : (E_r + (size_t)items_r[row] * 64 + (q - 2) * 32);
      u16* dst = xs + lr * 136 + q * 32;
      const float4* s4 = (const float4*)src;
#pragma unroll
      for (int h = 0; h < 8; h++) { float4 v = s4[h]; ushort4 u;
        u.x = f2bf(v.x); u.y = f2bf(v.y); u.z = f2bf(v.z); u.w = f2bf(v.w);
        *(ushort4*)(dst + h * 4) = u; }
    }
    f32x4 c3[4];
    mfma_3layers(lane, wave, xs, w1s, w2s, w3s, b1s, b2s, hs, c3);
    // xoa (with bias, no relu) -> hs
#pragma unroll
    for (int c = 0; c < 4; c++)
#pragma unroll
      for (int r = 0; r < 4; r++) {
        int rr = wave * 16 + quad * 4 + r;
        hs[rr * 72 + c * 16 + m] = f2bf(c3[c][r] + b3s[c * 16 + m]);
      }
    // coalesced bf16 xoa store: 16 rows x 64 u16 per wave
#pragma unroll
    for (int c2 = 0; c2 < 2; c2++) {
      int chunk = lane * 2 + c2;             // 0..127
      int row = chunk >> 3, k = chunk & 7;
      *(uint4*)(xoa_bf + ((size_t)(base + wave * 16 + row)) * 64 + k * 8) =
          *(const uint4*)(hs + (wave * 16 + row) * 72 + k * 8);
    }
    // fused attO score
    f32x4 c4[4];
#pragma unroll
    for (int c = 0; c < 4; c++) c4[c] = zz;
    int row = wave * 16 + m;
#pragma unroll
    for (int kk = 0; kk < 2; kk++) {
      short8v av = *(const short8v*)(hs + row * 72 + kk * 32 + quad * 8);
#pragma unroll
      for (int c = 0; c < 4; c++) {
        short8v bv = *(const short8v*)(was + (c * 16 + m) * 72 + kk * 32 + quad * 8);
        c4[c] = __builtin_amdgcn_mfma_f32_16x16x32_bf16(av, bv, c4[c], 0, 0, 0);
      }
    }
    float part[4] = {0.f, 0.f, 0.f, 0.f};
#pragma unroll
    for (int r = 0; r < 4; r++) {
      int gRow = base + wave * 16 + quad * 4 + r;
      int b_ = gRow / (GN * GN);
      int n2 = gRow % GN;
      const float* pw = poW + ((size_t)b_ * GN + n2) * 64;
#pragma unroll
      for (int c = 0; c < 4; c++) {
        int col = c * 16 + m;
        float h = c4[c][r] + pw[col] + ab1s[col];
        part[r] += fmaxf(h, 0.f) * aw2s[col];
      }
    }
#pragma unroll
    for (int r = 0; r < 4; r++) {
      float v = part[r];
      v += __shfl_xor(v, 1, 64); v += __shfl_xor(v, 2, 64);
      v += __shfl_xor(v, 4, 64); v += __shfl_xor(v, 8, 64);
      if (m == 0) sOut[base + wave * 16 + quad * 4 + r] = v + ab2v;
    }
  }
}

// pass2 (cheap): ho[b,n2] = relu( (sum_n1 alpha[b,n1,n2] * xoa[b,n1,n2,:]) @ linO + b )
__global__ __launch_bounds__(256) void k_ho(
    const u16* __restrict__ xoa_bf, const float* __restrict__ alpha,
    const float* __restrict__ linW, const float* __restrict__ linB,
    float* __restrict__ ho) {
  __shared__ float lws[64 * 64];
  __shared__ float lbs[64];
  __shared__ float ts[4][64];
  int t = threadIdx.x;
  for (int i = t; i < 4096; i += 256) lws[i] = linW[i];
  if (t < 64) lbs[t] = linB[t];
  __syncthreads();
  int lane = t & 63, wave = t >> 6;
  int gid = blockIdx.x * 4 + wave;          // 0 .. B*N-1
  int b_ = gid / GN, n2 = gid - b_ * GN;
  float acc = 0.f;
  for (int n1 = 0; n1 < GN; n1++) {
    size_t row = (size_t)(b_ * GN + n1) * GN + n2;
    float al = alpha[row];
    acc = fmaf(al, bf2f(xoa_bf[row * 64 + lane]), acc);
  }
  ts[wave][lane] = acc;   // wave-private LDS, in-order
  float o = lbs[lane];
#pragma unroll 8
  for (int k = 0; k < 64; k++) o = fmaf(ts[wave][k], lws[k * 64 + lane], o);
  ho[(size_t)gid * 64 + lane] = fmaxf(o, 0.f);
}

// ================= vector glue kernels =================
template <int R>
__device__ __forceinline__ void mlp3_rows(
    int lane, const float* const* pa, const float* const* pb,
    const u16* w1s, const u16* w2s, const u16* w3s,
    const float* b1s, const float* b2s, const float* b3s,
    float (*hbw)[GD], float* acc) {
#pragma unroll
  for (int r = 0; r < R; r++) acc[r] = b1s[lane];
#pragma unroll 8
  for (int k = 0; k < 64; k++) {
    float w = bf2f(w1s[k * 64 + lane]);
#pragma unroll
    for (int r = 0; r < R; r++) acc[r] = fmaf(pa[r][k], w, acc[r]);
  }
#pragma unroll 8
  for (int k = 0; k < 64; k++) {
    float w = bf2f(w1s[(64 + k) * 64 + lane]);
#pragma unroll
    for (int r = 0; r < R; r++) acc[r] = fmaf(pb[r][k], w, acc[r]);
  }
#pragma unroll
  for (int r = 0; r < R; r++) hbw[r][lane] = fmaxf(acc[r], 0.f);
#pragma unroll
  for (int r = 0; r < R; r++) acc[r] = b2s[lane];
#pragma unroll
  for (int kc = 0; kc < 16; kc++) {
    float w0 = bf2f(w2s[(kc * 4 + 0) * 64 + lane]);
    float w1 = bf2f(w2s[(kc * 4 + 1) * 64 + lane]);
    float w2 = bf2f(w2s[(kc * 4 + 2) * 64 + lane]);
    float w3 = bf2f(w2s[(kc * 4 + 3) * 64 + lane]);
#pragma unroll
    for (int r = 0; r < R; r++) {
      float4 x = *(const float4*)(&hbw[r][kc * 4]);
      acc[r] = fmaf(x.x, w0, fmaf(x.y, w1, fmaf(x.z, w2, fmaf(x.w, w3, acc[r]))));
    }
  }
#pragma unroll
  for (int r = 0; r < R; r++) hbw[r][lane] = fmaxf(acc[r], 0.f);
#pragma unroll
  for (int r = 0; r < R; r++) acc[r] = b3s[lane];
#pragma unroll
  for (int kc = 0; kc < 16; kc++) {
    float w0 = bf2f(w3s[(kc * 4 + 0) * 64 + lane]);
    float w1 = bf2f(w3s[(kc * 4 + 1) * 64 + lane]);
    float w2 = bf2f(w3s[(kc * 4 + 2) * 64 + lane]);
    float w3 = bf2f(w3s[(kc * 4 + 3) * 64 + lane]);
#pragma unroll
    for (int r = 0; r < R; r++) {
      float4 x = *(const float4*)(&hbw[r][kc * 4]);
      acc[r] = fmaf(x.x, w0, fmaf(x.y, w1, fmaf(x.z, w2, fmaf(x.w, w3, acc[r]))));
    }
  }
}

__global__ __launch_bounds__(256, 4) void k_rowlin(
    int M, const float* __restrict__ tab, const int* __restrict__ idx,
    const float* __restrict__ W, float* __restrict__ out) {
  __shared__ float ws[64 * 64];
  for (int i = threadIdx.x; i < 64 * 64; i += 256) ws[i] = W[i];
  __syncthreads();
  const int lane = threadIdx.x & 63, wave = threadIdx.x >> 6;
  int base0 = (blockIdx.x * 4 + wave) * 8;
  if (base0 >= M) return;
  const float* p[8];
#pragma unroll
  for (int r = 0; r < 8; r++) {
    int ia = __builtin_amdgcn_readfirstlane(idx[base0 + r]);
    p[r] = tab + (size_t)ia * 64;
  }
  float acc[8];
#pragma unroll
  for (int r = 0; r < 8; r++) acc[r] = 0.f;
#pragma unroll 8
  for (int k = 0; k < 64; k++) {
    float w = ws[k * 64 + lane];
#pragma unroll
    for (int r = 0; r < 8; r++) acc[r] = fmaf(p[r][k], w, acc[r]);
  }
#pragma unroll
  for (int r = 0; r < 8; r++) out[(size_t)(base0 + r) * 64 + lane] = acc[r];
}

__global__ __launch_bounds__(512, 2) void k_mlp3(
    int M,
    const float* __restrict__ tabA, const int* __restrict__ idxA,
    const float* __restrict__ tabB, const int* __restrict__ idxB,
    const float* __restrict__ W1, const float* __restrict__ b1,
    const float* __restrict__ W2, const float* __restrict__ b2,
    const float* __restrict__ W3, const float* __restrict__ b3,
    float* __restrict__ out) {
  __shared__ u16 w1s[128 * 64], w2s[64 * 64], w3s[64 * 64];
  __shared__ float b1s[64], b2s[64], b3s[64];
  __shared__ float hb[8][8][GD];
  for (int i = threadIdx.x; i < 128 * 64; i += 512) w1s[i] = f2bf(W1[i]);
  for (int i = threadIdx.x; i < 64 * 64; i += 512) { w2s[i] = f2bf(W2[i]); w3s[i] = f2bf(W3[i]); }
  if (threadIdx.x < 64) { b1s[threadIdx.x] = b1[threadIdx.x]; b2s[threadIdx.x] = b2[threadIdx.x]; b3s[threadIdx.x] = b3[threadIdx.x]; }
  __syncthreads();
  const int lane = threadIdx.x & 63, wave = threadIdx.x >> 6;
  for (int base = blockIdx.x * 64; base < M; base += gridDim.x * 64) {
    int rb = base + wave * 8;
    const float* pa[8]; const float* pb[8];
#pragma unroll
    for (int r = 0; r < 8; r++) {
      int row = rb + r;
      int ia = idxA ? idxA[row] : row;
      pa[r] = tabA + (size_t)__builtin_amdgcn_readfirstlane(ia) * 64;
      int ib = idxB ? idxB[row] : row;
      pb[r] = tabB + (size_t)__builtin_amdgcn_readfirstlane(ib) * 64;
    }
    float acc[8];
    mlp3_rows<8>(lane, pa, pb, w1s, w2s, w3s, b1s, b2s, b3s, hb[wave], acc);
#pragma unroll
    for (int r = 0; r < 8; r++) out[(size_t)(rb + r) * 64 + lane] = acc[r];
  }
}

__global__ __launch_bounds__(256, 4) void k_score(
    int M, const float* __restrict__ selfW, const float* __restrict__ X,
    const float* __restrict__ W1b, const float* __restrict__ b1,
    const float* __restrict__ W2, const float* __restrict__ b2,
    float* __restrict__ sOut) {
  __shared__ float ws[64 * 64];
  __shared__ float w2s[64], b1s[64];
  for (int i = threadIdx.x; i < 64 * 64; i += 256) ws[i] = W1b[i];
  if (threadIdx.x < 64) { w2s[threadIdx.x] = W2[threadIdx.x]; b1s[threadIdx.x] = b1[threadIdx.x]; }
  __syncthreads();
  const int lane = threadIdx.x & 63, wave = threadIdx.x >> 6;
  int rb = (blockIdx.x * 4 + wave) * 8;
  if (rb >= M) return;
  const float* px[8]; float acc[8];
#pragma unroll
  for (int r = 0; r < 8; r++) {
    int row = rb + r;
    px[r] = X + (size_t)row * 64;
    acc[r] = b1s[lane] + selfW[(size_t)(row / GN) * 64 + lane];
  }
#pragma unroll 8
  for (int k = 0; k < 64; k++) {
    float w = ws[k * 64 + lane];
#pragma unroll
    for (int r = 0; r < 8; r++) acc[r] = fmaf(px[r][k], w, acc[r]);
  }
  float bb2 = b2[0];
#pragma unroll
  for (int r = 0; r < 8; r++) {
    float v = fmaxf(acc[r], 0.f) * w2s[lane];
    v = wave_sum(v);
    if (lane == 0) sOut[rb + r] = v + bb2;
  }
}

__global__ __launch_bounds__(256) void k_softmax_col(float* __restrict__ s, int C) {
  int c = blockIdx.x, t = threadIdx.x;
  int lane = t & 63, wave = t >> 6;
  float v0 = s[(size_t)t * C + c];
  float v1 = s[(size_t)(t + 256) * C + c];
  float m = fmaxf(v0, v1);
#pragma unroll
  for (int off = 32; off >= 1; off >>= 1) m = fmaxf(m, __shfl_xor(m, off, 64));
  __shared__ float rm[4], rs[4];
  if (lane == 0) rm[wave] = m;
  __syncthreads();
  float M4 = fmaxf(fmaxf(rm[0], rm[1]), fmaxf(rm[2], rm[3]));
  float e0 = expf(v0 - M4), e1 = expf(v1 - M4);
  float sm = wave_sum(e0 + e1);
  if (lane == 0) rs[wave] = sm;
  __syncthreads();
  float inv = 1.f / (rs[0] + rs[1] + rs[2] + rs[3]);
  s[(size_t)t * C + c] = e0 * inv;
  s[(size_t)(t + 256) * C + c] = e1 * inv;
}

__global__ __launch_bounds__(64) void k_wsum_lin(
    int C, const float* __restrict__ alpha, const float* __restrict__ X,
    const float* __restrict__ W, const float* __restrict__ bias,
    float* __restrict__ out) {
  int b = blockIdx.x, l = threadIdx.x;
  float t = 0.f;
  for (int n = 0; n < C; n++) t = fmaf(alpha[b * C + n], X[((size_t)b * C + n) * 64 + l], t);
  __shared__ float ts[64];
  ts[l] = t;
  float acc = bias[l];
#pragma unroll 8
  for (int k = 0; k < 64; k++) acc = fmaf(ts[k], W[k * 64 + l], acc);
  out[(size_t)b * 64 + l] = fmaxf(acc, 0.f);
}

__global__ __launch_bounds__(256) void k_final(
    const float* __restrict__ hi, const float* __restrict__ zj,
    const float* __restrict__ gW1, const float* __restrict__ gb1,
    const float* __restrict__ gW2, const float* __restrict__ gb2,
    const float* __restrict__ gW3, const float* __restrict__ gb3,
    float* __restrict__ out) {
  const int lane = threadIdx.x & 63, wave = threadIdx.x >> 6;
  int b = blockIdx.x * 4 + wave;
  float v = hi[(size_t)b * 64 + lane] * gW1[lane] + zj[(size_t)b * 64 + lane] * gW1[64 + lane];
  v = wave_sum(v);
  if (lane == 0) {
    float h = fmaxf(v + gb1[0], 0.f);
    h = fmaxf(h * gW2[0] + gb2[0], 0.f);
    out[b] = h * gW3[0] + gb3[0];
  }
}

extern "C" void kernel_launch(void* const* d_in, const int* in_sizes, int n_in,
                              void* d_out, int out_size, void* d_ws, size_t ws_size,
                              hipStream_t stream) {
  const float* E_u = (const float*)d_in[0];
  const float* E_i = (const float*)d_in[1];
  const float* E_r = (const float*)d_in[2];
  const float* gvW1 = (const float*)d_in[3];  const float* gvb1 = (const float*)d_in[4];
  const float* gvW2 = (const float*)d_in[5];  const float* gvb2 = (const float*)d_in[6];
  const float* gvW3 = (const float*)d_in[7];  const float* gvb3 = (const float*)d_in[8];
  const float* umW1 = (const float*)d_in[9];  const float* umb1 = (const float*)d_in[10];
  const float* umW2 = (const float*)d_in[11]; const float* umb2 = (const float*)d_in[12];
  const float* umW3 = (const float*)d_in[13]; const float* umb3 = (const float*)d_in[14];
  const float* guW1 = (const float*)d_in[15]; const float* gub1 = (const float*)d_in[16];
  const float* guW2 = (const float*)d_in[17]; const float* gub2 = (const float*)d_in[18];
  const float* guW3 = (const float*)d_in[19]; const float* gub3 = (const float*)d_in[20];
  const float* aIW1 = (const float*)d_in[21]; const float* aIb1 = (const float*)d_in[22];
  const float* aIW2 = (const float*)d_in[23]; const float* aIb2 = (const float*)d_in[24];
  const float* aOW1 = (const float*)d_in[25]; const float* aOb1 = (const float*)d_in[26];
  const float* aOW2 = (const float*)d_in[27]; const float* aOb2 = (const float*)d_in[28];
  const float* aSW1 = (const float*)d_in[29]; const float* aSb1 = (const float*)d_in[30];
  const float* aSW2 = (const float*)d_in[31]; const float* aSb2 = (const float*)d_in[32];
  const float* aiW1 = (const float*)d_in[33]; const float* aib1 = (const float*)d_in[34];
  const float* aiW2 = (const float*)d_in[35]; const float* aib2 = (const float*)d_in[36];
  const float* linIW = (const float*)d_in[37]; const float* linIb = (const float*)d_in[38];
  const float* linOW = (const float*)d_in[39]; const float* linOb = (const float*)d_in[40];
  const float* ilinW = (const float*)d_in[41]; const float* ilinb = (const float*)d_in[42];
  const float* gW1 = (const float*)d_in[43]; const float* gb1 = (const float*)d_in[44];
  const float* gW2 = (const float*)d_in[45]; const float* gb2 = (const float*)d_in[46];
  const float* gW3 = (const float*)d_in[47]; const float* gb3 = (const float*)d_in[48];
  const int* nodes_u = (const int*)d_in[49];
  const int* nodes_i = (const int*)d_in[50];
  const int* u_items = (const int*)d_in[51];
  const int* u_users = (const int*)d_in[52];
  const int* i_users = (const int*)d_in[53];
  const int* u_items_r = (const int*)d_in[54];
  const int* uu_items = (const int*)d_in[55];
  const int* uu_items_r = (const int*)d_in[56];
  const int* i_users_r = (const int*)d_in[57];
  float* out = (float*)d_out;

  // workspace carve-up
  float* p = (float*)d_ws;
  float* piWI = p; p += GB * GD;
  float* piWS = p; p += GB * GD;
  float* qjWi = p; p += GB * GD;
  float* poW  = p; p += GB * GN * GD;
  float* xia  = p; p += GB * GN * GD;
  float* fjt  = p; p += GB * GN * GD;
  float* ho   = p; p += GB * GN * GD;
  float* sI   = p; p += GB * GN;
  float* sS   = p; p += GB * GN;
  float* si   = p; p += GB * GN;
  float* sO   = p; p += GB * GN * GN;
  float* hiI  = p; p += GB * GD;
  float* hiS  = p; p += GB * GD;
  float* hi   = p; p += GB * GD;
  float* zj   = p; p += GB * GD;
  u16* q16 = (u16*)p;
  u16* gv1t = q16; q16 += 8192;
  u16* gv2t = q16; q16 += 4096;
  u16* gv3t = q16; q16 += 4096;
  u16* aot  = q16; q16 += 4096;
  u16* gu1t = q16; q16 += 8192;
  u16* gu2t = q16; q16 += 4096;
  u16* gu3t = q16; q16 += 4096;
  u16* xoa_bf = q16; q16 += (size_t)GB * GN * GN * GD;   // 59 MB

  const int BN = GB * GN;           // 15360
  const int M2 = GB * GN * GN;      // 460800

  k_prep<<<144, 256, 0, stream>>>(gvW1, gvW2, gvW3, aOW1, guW1, guW2, guW3,
                                  gv1t, gv2t, gv3t, aot, gu1t, gu2t, gu3t);
  k_rowlin<<<GB / 32, 256, 0, stream>>>(GB, E_u, nodes_u, aIW1, piWI);
  k_rowlin<<<GB / 32, 256, 0, stream>>>(GB, E_u, nodes_u, aSW1, piWS);
  k_rowlin<<<GB / 32, 256, 0, stream>>>(GB, E_i, nodes_i, aiW1, qjWi);
  k_rowlin<<<BN / 32, 256, 0, stream>>>(BN, E_u, u_users, aOW1, poW);

  // item-space aggregation
  k_mlp3_mfma<<<BN / 64, 256, 0, stream>>>(E_i, u_items, E_r, u_items_r,
                                           gv1t, gv2t, gv3t, gvb1, gvb2, gvb3, xia);
  k_score<<<BN / 32, 256, 0, stream>>>(BN, piWI, xia, aIW1 + 64 * 64, aIb1, aIW2, aIb2, sI);
  k_softmax_col<<<GN, 256, 0, stream>>>(sI, GN);
  k_wsum_lin<<<GB, 64, 0, stream>>>(GN, sI, xia, linIW, linIb, hiI);

  // social-space aggregation (persistent pass1, cheap pass2)
  k_xoa1_mfma<<<512, 256, 0, stream>>>(E_i, E_r, uu_items, uu_items_r,
                                       gv1t, gv2t, gv3t, gvb1, gvb2, gvb3,
                                       aot, aOb1, aOW2, aOb2, poW, xoa_bf, sO);
  k_softmax_col<<<GN * GN, 256, 0, stream>>>(sO, GN * GN);
  k_ho<<<BN / 4, 256, 0, stream>>>(xoa_bf, sO, linOW, linOb, ho);
  k_score<<<BN / 32, 256, 0, stream>>>(BN, piWS, ho, aSW1 + 64 * 64, aSb1, aSW2, aSb2, sS);
  k_softmax_col<<<GN, 256, 0, stream>>>(sS, GN);
  k_wsum_lin<<<GB, 64, 0, stream>>>(GN, sS, ho, linOW, linOb, hiS);
  k_mlp3<<<GB / 64, 512, 0, stream>>>(GB, hiI, nullptr, hiS, nullptr,
                                      umW1, umb1, umW2, umb2, umW3, umb3, hi);

  // item modeling
  k_mlp3_mfma<<<BN / 64, 256, 0, stream>>>(E_u, i_users, E_r, i_users_r,
                                           gu1t, gu2t, gu3t, gub1, gub2, gub3, fjt);
  k_score<<<BN / 32, 256, 0, stream>>>(BN, qjWi, fjt, aiW1 + 64 * 64, aib1, aiW2, aib2, si);
  k_softmax_col<<<GN, 256, 0, stream>>>(si, GN);
  k_wsum_lin<<<GB, 64, 0, stream>>>(GN, si, fjt, ilinW, ilinb, zj);

  k_final<<<GB / 4, 256, 0, stream>>>(hi, zj, gW1, gb1, gW2, gb2, gW3, gb3, out);
}

// Round 4
// 616.455 us; speedup vs baseline: 2.3595x; 1.1718x over previous
//
#include <hip/hip_runtime.h>
#include <cstdint>
#include <cstddef>

// GraphRec forward, 8 launches total.
// Engine: persistent MFMA kernel, register-held L2/L3/att weight fragments,
// software-pipelined gathers, fused attention scores, bf16 outputs.
// Hidden-state LDS layout uses position permutation korig(p)=(p&3)*16+(p>>2),
// baked into the pre-transposed weights; consumers read cols via IDX16.

#define GB 512
#define GN 30
#define GD 64
#define IDX16(l) ((((l) & 15) << 2) | ((l) >> 4))

typedef unsigned short u16;
typedef __attribute__((ext_vector_type(8))) short short8v;  // 8 bf16
typedef __attribute__((ext_vector_type(4))) float f32x4;

__device__ __forceinline__ u16 f2bf(float x) {
  union { float f; uint32_t u; } c; c.f = x;
  uint32_t r = c.u + 0x7fffu + ((c.u >> 16) & 1u);
  return (u16)(r >> 16);
}
__device__ __forceinline__ float bf2f(u16 b) {
  union { float f; uint32_t u; } c; c.u = ((uint32_t)b) << 16; return c.f;
}
__device__ __forceinline__ float wave_sum(float v) {
#pragma unroll
  for (int off = 32; off >= 1; off >>= 1) v += __shfl_xor(v, off, 64);
  return v;
}

// =============== 1. setup: weight transpose/permute + rowlin precomputes ===============
__global__ __launch_bounds__(256) void k_setup(
    const float* __restrict__ gvW1, const float* __restrict__ gvW2, const float* __restrict__ gvW3,
    const float* __restrict__ guW1, const float* __restrict__ guW2, const float* __restrict__ guW3,
    const float* __restrict__ umW1, const float* __restrict__ umW2, const float* __restrict__ umW3,
    const float* __restrict__ aOW1, const float* __restrict__ aIW1, const float* __restrict__ aiW1,
    const float* __restrict__ aSW1,
    const float* __restrict__ E_u, const float* __restrict__ E_i,
    const int* __restrict__ nodes_u, const int* __restrict__ nodes_i, const int* __restrict__ u_users,
    u16* gv1t, u16* gv2t, u16* gv3t, u16* gu1t, u16* gu2t, u16* gu3t,
    u16* um1t, u16* um2t, u16* um3t, u16* aOt, u16* aIt, u16* ait,
    float* piWI, float* piWS, float* qjWi, float* poW) {
  __shared__ float ws[64 * 64];
  int blk = blockIdx.x, t = threadIdx.x;
  if (blk < 240) {  // weight prep: 61440 elements
    int o = blk * 256 + t;
    const float* src; u16* dst; int kind;  // 0: K=128 plain; 1: K=64 permuted; 2: att bottom-half permuted
    if      (o < 8192)  {            src = gvW1; dst = gv1t; kind = 0; }
    else if (o < 12288) { o -= 8192;  src = gvW2; dst = gv2t; kind = 1; }
    else if (o < 16384) { o -= 12288; src = gvW3; dst = gv3t; kind = 1; }
    else if (o < 20480) { o -= 16384; src = aOW1; dst = aOt;  kind = 2; }
    else if (o < 28672) { o -= 20480; src = guW1; dst = gu1t; kind = 0; }
    else if (o < 32768) { o -= 28672; src = guW2; dst = gu2t; kind = 1; }
    else if (o < 36864) { o -= 32768; src = guW3; dst = gu3t; kind = 1; }
    else if (o < 40960) { o -= 36864; src = aIW1; dst = aIt;  kind = 2; }
    else if (o < 45056) { o -= 40960; src = aiW1; dst = ait;  kind = 2; }
    else if (o < 53248) { o -= 45056; src = umW1; dst = um1t; kind = 0; }
    else if (o < 57344) { o -= 53248; src = umW2; dst = um2t; kind = 1; }
    else                { o -= 57344; src = umW3; dst = um3t; kind = 1; }
    if (kind == 0) { int n = o >> 7, k = o & 127; dst[n * 128 + k] = f2bf(src[(size_t)k * 64 + n]); }
    else { int n = o >> 6, p = o & 63; int k = ((p & 3) << 4) | (p >> 2); if (kind == 2) k += 64;
           dst[n * 64 + p] = f2bf(src[(size_t)k * 64 + n]); }
    return;
  }
  // rowlin: out[r] = tab[idx[r]] @ W_top64
  int rb = blk - 240;
  const float* tab; const int* idx; const float* W; float* out; int base;
  if (rb < 16)      { tab = E_u; idx = nodes_u; W = aIW1; out = piWI; base = rb * 32; }
  else if (rb < 32) { tab = E_u; idx = nodes_u; W = aSW1; out = piWS; base = (rb - 16) * 32; }
  else if (rb < 48) { tab = E_i; idx = nodes_i; W = aiW1; out = qjWi; base = (rb - 32) * 32; }
  else              { tab = E_u; idx = u_users; W = aOW1; out = poW;  base = (rb - 48) * 32; }
  for (int i = t; i < 4096; i += 256) ws[i] = W[i];
  __syncthreads();
  int lane = t & 63, wave = t >> 6;
  int b0 = base + wave * 8;
  const float* p[8]; float acc[8];
#pragma unroll
  for (int r = 0; r < 8; r++) {
    p[r] = tab + (size_t)__builtin_amdgcn_readfirstlane(idx[b0 + r]) * 64;
    acc[r] = 0.f;
  }
#pragma unroll 8
  for (int k = 0; k < 64; k++) {
    float w = ws[k * 64 + lane];
#pragma unroll
    for (int r = 0; r < 8; r++) acc[r] = fmaf(p[r][k], w, acc[r]);
  }
#pragma unroll
  for (int r = 0; r < 8; r++) out[(size_t)(b0 + r) * 64 + lane] = acc[r];
}

// =============== 2. engine: all row-MLPs + fused att scores ===============
__global__ __launch_bounds__(256, 2) void k_engine(
    const float* __restrict__ E_i, const float* __restrict__ E_r, const float* __restrict__ E_u,
    const int* __restrict__ uu_items, const int* __restrict__ uu_items_r,
    const int* __restrict__ u_items, const int* __restrict__ u_items_r,
    const int* __restrict__ i_users, const int* __restrict__ i_users_r,
    const u16* __restrict__ gv1t, const u16* __restrict__ gv2t, const u16* __restrict__ gv3t,
    const u16* __restrict__ gu1t, const u16* __restrict__ gu2t, const u16* __restrict__ gu3t,
    const float* __restrict__ gvb1, const float* __restrict__ gvb2, const float* __restrict__ gvb3,
    const float* __restrict__ gub1, const float* __restrict__ gub2, const float* __restrict__ gub3,
    const u16* __restrict__ aOt, const u16* __restrict__ aIt, const u16* __restrict__ ait,
    const float* __restrict__ aOb1, const float* __restrict__ aIb1, const float* __restrict__ aib1,
    const float* __restrict__ aOW2, const float* __restrict__ aIW2, const float* __restrict__ aiW2,
    const float* __restrict__ aOb2, const float* __restrict__ aIb2, const float* __restrict__ aib2,
    const float* __restrict__ poW, const float* __restrict__ piWI, const float* __restrict__ qjWi,
    u16* __restrict__ xoa_bf, u16* __restrict__ xia_bf, u16* __restrict__ fjt_bf,
    float* __restrict__ sOT, float* __restrict__ sIT, float* __restrict__ siT) {
  __shared__ __align__(16) u16 xs[64 * 136], w1s[64 * 136], hs[64 * 72];
  __shared__ float b1s[64], b2s[64], b3s[64], ab1s[64], aw2s[64];
  int t = threadIdx.x, blk = blockIdx.x;
  const float *tabA, *tabB, *selfW, *b1, *b2, *b3, *ab1, *aW2, *ab2p;
  const int *idxA, *idxB; const u16 *w1t, *w2t, *w3t, *att;
  u16* outB; float* sT; int tile0, modeNN;
  if (blk < 480) {
    tabA = E_i; idxA = uu_items; tabB = E_r; idxB = uu_items_r;
    w1t = gv1t; w2t = gv2t; w3t = gv3t; b1 = gvb1; b2 = gvb2; b3 = gvb3;
    att = aOt; ab1 = aOb1; aW2 = aOW2; ab2p = aOb2; selfW = poW;
    outB = xoa_bf; sT = sOT; tile0 = blk * 15; modeNN = 1;
  } else if (blk < 496) {
    int lb = blk - 480;
    tabA = E_i; idxA = u_items; tabB = E_r; idxB = u_items_r;
    w1t = gv1t; w2t = gv2t; w3t = gv3t; b1 = gvb1; b2 = gvb2; b3 = gvb3;
    att = aIt; ab1 = aIb1; aW2 = aIW2; ab2p = aIb2; selfW = piWI;
    outB = xia_bf; sT = sIT; tile0 = lb * 15; modeNN = 0;
  } else {
    int lb = blk - 496;
    tabA = E_u; idxA = i_users; tabB = E_r; idxB = i_users_r;
    w1t = gu1t; w2t = gu2t; w3t = gu3t; b1 = gub1; b2 = gub2; b3 = gub3;
    att = ait; ab1 = aib1; aW2 = aiW2; ab2p = aib2; selfW = qjWi;
    outB = fjt_bf; sT = siT; tile0 = lb * 15; modeNN = 0;
  }
  const int nt = 15;
  for (int i = t; i < 64 * 16; i += 256) { int n = i >> 4, j = i & 15;
    ((uint4*)(w1s + n * 136))[j] = ((const uint4*)(w1t + n * 128))[j]; }
  if (t < 64) { b1s[t] = b1[t]; b2s[t] = b2[t]; b3s[t] = b3[t];
                ab1s[t] = ab1[t]; aw2s[t] = aW2[t]; }
  __syncthreads();   // weights ready; all below is wave-private
  const int lane = t & 63, wave = t >> 6, m = lane & 15, quad = lane >> 4;
  const int lr = t >> 2, q = t & 3;
  // register B-fragments (position space, matches permuted weight prep)
  short8v w2f[8], w3f[8], waf[8];
#pragma unroll
  for (int c = 0; c < 4; c++)
#pragma unroll
    for (int kk = 0; kk < 2; kk++) {
      int off = (c * 16 + m) * 64 + kk * 32 + quad * 8;
      w2f[c * 2 + kk] = *(const short8v*)(w2t + off);
      w3f[c * 2 + kk] = *(const short8v*)(w3t + off);
      waf[c * 2 + kk] = *(const short8v*)(att + off);
    }
  const float ab2v = ab2p[0];
  const f32x4 zz = {0.f, 0.f, 0.f, 0.f};
  // prefetch tile 0
  float4 fr[8];
  {
    int row = tile0 * 64 + lr;
    const float* src = (q < 2) ? (tabA + (size_t)idxA[row] * 64 + q * 32)
                               : (tabB + (size_t)idxB[row] * 64 + (q - 2) * 32);
#pragma unroll
    for (int h = 0; h < 8; h++) fr[h] = ((const float4*)src)[h];
  }
  for (int it = 0; it < nt; it++) {
    int base = (tile0 + it) * 64;
    // stage current tile
    { u16* dst = xs + lr * 136 + q * 32;
#pragma unroll
      for (int h = 0; h < 8; h++) { float4 v = fr[h]; ushort4 u;
        u.x = f2bf(v.x); u.y = f2bf(v.y); u.z = f2bf(v.z); u.w = f2bf(v.w);
        *(ushort4*)(dst + h * 4) = u; } }
    // prefetch next tile (in flight during compute)
    if (it + 1 < nt) {
      int row = base + 64 + lr;
      const float* src = (q < 2) ? (tabA + (size_t)idxA[row] * 64 + q * 32)
                                 : (tabB + (size_t)idxB[row] * 64 + (q - 2) * 32);
#pragma unroll
      for (int h = 0; h < 8; h++) fr[h] = ((const float4*)src)[h];
    }
    // layer 1 (K=128): A from xs, B from w1s
    f32x4 cc[4];
#pragma unroll
    for (int c = 0; c < 4; c++) cc[c] = zz;
#pragma unroll
    for (int kk = 0; kk < 4; kk++) {
      short8v av = *(const short8v*)(xs + (wave * 16 + m) * 136 + kk * 32 + quad * 8);
#pragma unroll
      for (int c = 0; c < 4; c++) {
        short8v bv = *(const short8v*)(w1s + (c * 16 + m) * 136 + kk * 32 + quad * 8);
        cc[c] = __builtin_amdgcn_mfma_f32_16x16x32_bf16(av, bv, cc[c], 0, 0, 0);
      }
    }
#pragma unroll
    for (int r = 0; r < 4; r++) { ushort4 u;
      u.x = f2bf(fmaxf(cc[0][r] + b1s[m], 0.f));
      u.y = f2bf(fmaxf(cc[1][r] + b1s[16 + m], 0.f));
      u.z = f2bf(fmaxf(cc[2][r] + b1s[32 + m], 0.f));
      u.w = f2bf(fmaxf(cc[3][r] + b1s[48 + m], 0.f));
      *(ushort4*)(hs + (wave * 16 + quad * 4 + r) * 72 + m * 4) = u; }
    // layer 2 (K=64): B from registers
#pragma unroll
    for (int c = 0; c < 4; c++) cc[c] = zz;
#pragma unroll
    for (int kk = 0; kk < 2; kk++) {
      short8v av = *(const short8v*)(hs + (wave * 16 + m) * 72 + kk * 32 + quad * 8);
#pragma unroll
      for (int c = 0; c < 4; c++)
        cc[c] = __builtin_amdgcn_mfma_f32_16x16x32_bf16(av, w2f[c * 2 + kk], cc[c], 0, 0, 0);
    }
#pragma unroll
    for (int r = 0; r < 4; r++) { ushort4 u;
      u.x = f2bf(fmaxf(cc[0][r] + b2s[m], 0.f));
      u.y = f2bf(fmaxf(cc[1][r] + b2s[16 + m], 0.f));
      u.z = f2bf(fmaxf(cc[2][r] + b2s[32 + m], 0.f));
      u.w = f2bf(fmaxf(cc[3][r] + b2s[48 + m], 0.f));
      *(ushort4*)(hs + (wave * 16 + quad * 4 + r) * 72 + m * 4) = u; }
    // layer 3 (K=64, no relu)
    f32x4 c3[4];
#pragma unroll
    for (int c = 0; c < 4; c++) c3[c] = zz;
#pragma unroll
    for (int kk = 0; kk < 2; kk++) {
      short8v av = *(const short8v*)(hs + (wave * 16 + m) * 72 + kk * 32 + quad * 8);
#pragma unroll
      for (int c = 0; c < 4; c++)
        c3[c] = __builtin_amdgcn_mfma_f32_16x16x32_bf16(av, w3f[c * 2 + kk], c3[c], 0, 0, 0);
    }
#pragma unroll
    for (int r = 0; r < 4; r++) { ushort4 u;
      u.x = f2bf(c3[0][r] + b3s[m]);
      u.y = f2bf(c3[1][r] + b3s[16 + m]);
      u.z = f2bf(c3[2][r] + b3s[32 + m]);
      u.w = f2bf(c3[3][r] + b3s[48 + m]);
      *(ushort4*)(hs + (wave * 16 + quad * 4 + r) * 72 + m * 4) = u; }
    // coalesced bf16 store (permuted positions; consumers use IDX16)
#pragma unroll
    for (int c2 = 0; c2 < 2; c2++) {
      int chunk = lane * 2 + c2; int row = chunk >> 3, k8 = chunk & 7;
      *(uint4*)(outB + ((size_t)(base + wave * 16 + row)) * 64 + k8 * 8) =
          *(const uint4*)(hs + (wave * 16 + row) * 72 + k8 * 8);
    }
    // fused att score
    f32x4 c4[4];
#pragma unroll
    for (int c = 0; c < 4; c++) c4[c] = zz;
#pragma unroll
    for (int kk = 0; kk < 2; kk++) {
      short8v av = *(const short8v*)(hs + (wave * 16 + m) * 72 + kk * 32 + quad * 8);
#pragma unroll
      for (int c = 0; c < 4; c++)
        c4[c] = __builtin_amdgcn_mfma_f32_16x16x32_bf16(av, waf[c * 2 + kk], c4[c], 0, 0, 0);
    }
    float part[4];
#pragma unroll
    for (int r = 0; r < 4; r++) {
      int gRow = base + wave * 16 + quad * 4 + r;
      int sidx = modeNN ? ((gRow / (GN * GN)) * GN + gRow % GN) : (gRow / GN);
      const float* pw = selfW + (size_t)sidx * 64;
      float s = 0.f;
#pragma unroll
      for (int c = 0; c < 4; c++) {
        int col = c * 16 + m;
        s += fmaxf(c4[c][r] + pw[col] + ab1s[col], 0.f) * aw2s[col];
      }
      part[r] = s;
    }
#pragma unroll
    for (int r = 0; r < 4; r++) {
      float v = part[r];
      v += __shfl_xor(v, 1, 64); v += __shfl_xor(v, 2, 64);
      v += __shfl_xor(v, 4, 64); v += __shfl_xor(v, 8, 64);
      if (m == 0) {
        int gRow = base + wave * 16 + quad * 4 + r;
        int scol, sb;
        if (modeNN) { sb = gRow / (GN * GN); scol = gRow % (GN * GN); }
        else        { sb = gRow / GN;        scol = gRow % GN; }
        sT[(size_t)scol * GB + sb] = v + ab2v;
      }
    }
  }
}

// =============== 3. softmax over batch axis (columns contiguous) ===============
__global__ __launch_bounds__(256) void k_softmax_t(
    float* __restrict__ sIT, float* __restrict__ siT, float* __restrict__ sOT) {
  int blk = blockIdx.x, t = threadIdx.x;
  float* p;
  if (blk < 30)      p = sIT + (size_t)blk * GB;
  else if (blk < 60) p = siT + (size_t)(blk - 30) * GB;
  else               p = sOT + (size_t)(blk - 60) * GB;
  int lane = t & 63, wave = t >> 6;
  float v0 = p[t], v1 = p[t + 256];
  float mx = fmaxf(v0, v1);
#pragma unroll
  for (int off = 32; off >= 1; off >>= 1) mx = fmaxf(mx, __shfl_xor(mx, off, 64));
  __shared__ float rm[4], rs[4];
  if (lane == 0) rm[wave] = mx;
  __syncthreads();
  float M4 = fmaxf(fmaxf(rm[0], rm[1]), fmaxf(rm[2], rm[3]));
  float e0 = expf(v0 - M4), e1 = expf(v1 - M4);
  float sm = wave_sum(e0 + e1);
  if (lane == 0) rs[wave] = sm;
  __syncthreads();
  float inv = 1.f / (rs[0] + rs[1] + rs[2] + rs[3]);
  p[t] = e0 * inv;
  p[t + 256] = e1 * inv;
}

// =============== 4. agg: hiI + zj (wsum+lin from bf16) and ho (from xoa) ===============
__global__ __launch_bounds__(256) void k_agg(
    const u16* __restrict__ xia_bf, const u16* __restrict__ fjt_bf, const u16* __restrict__ xoa_bf,
    const float* __restrict__ sIT, const float* __restrict__ siT, const float* __restrict__ sOT,
    const float* __restrict__ linIW, const float* __restrict__ linIb,
    const float* __restrict__ ilinW, const float* __restrict__ ilinb,
    const float* __restrict__ linOW, const float* __restrict__ linOb,
    float* __restrict__ hiI, float* __restrict__ zj, float* __restrict__ ho) {
  __shared__ float ws[64 * 64];
  __shared__ float ts[4][64];
  int blk = blockIdx.x, t = threadIdx.x, lane = t & 63, wave = t >> 6;
  const float* W; const float* bias;
  if (blk < 128)      { W = linIW; bias = linIb; }
  else if (blk < 256) { W = ilinW; bias = ilinb; }
  else                { W = linOW; bias = linOb; }
  for (int i = t; i < 4096; i += 256) ws[i] = W[i];
  __syncthreads();
  int px = IDX16(lane);
  float acc = 0.f;
  float* outp;
  if (blk < 256) {
    int b = (blk & 127) * 4 + wave;
    const u16* X = (blk < 128) ? xia_bf : fjt_bf;
    const float* al = (blk < 128) ? sIT : siT;
    for (int n = 0; n < GN; n++)
      acc = fmaf(al[(size_t)n * GB + b], bf2f(X[((size_t)b * GN + n) * 64 + px]), acc);
    outp = ((blk < 128) ? hiI : zj) + (size_t)b * 64;
  } else {
    int gid = (blk - 256) * 4 + wave;
    int b_ = gid / GN, n2 = gid - b_ * GN;
    for (int n1 = 0; n1 < GN; n1++)
      acc = fmaf(sOT[((size_t)(n1 * GN + n2)) * GB + b_],
                 bf2f(xoa_bf[(((size_t)b_ * GN + n1) * GN + n2) * 64 + px]), acc);
    outp = ho + (size_t)gid * 64;
  }
  ts[wave][lane] = acc;  // wave-private, in-order DS
  float o = bias[lane];
#pragma unroll 8
  for (int k = 0; k < 64; k++) o = fmaf(ts[wave][k], ws[k * 64 + lane], o);
  outp[lane] = fmaxf(o, 0.f);
}

// =============== 5. score sS (fp32 ho path, transposed output) ===============
__global__ __launch_bounds__(256, 4) void k_score_sS(
    const float* __restrict__ selfW, const float* __restrict__ X,
    const float* __restrict__ W1b, const float* __restrict__ b1,
    const float* __restrict__ W2, const float* __restrict__ b2,
    float* __restrict__ sT) {
  __shared__ float ws[64 * 64];
  __shared__ float w2s[64], b1s[64];
  for (int i = threadIdx.x; i < 64 * 64; i += 256) ws[i] = W1b[i];
  if (threadIdx.x < 64) { w2s[threadIdx.x] = W2[threadIdx.x]; b1s[threadIdx.x] = b1[threadIdx.x]; }
  __syncthreads();
  const int lane = threadIdx.x & 63, wave = threadIdx.x >> 6;
  int rb = (blockIdx.x * 4 + wave) * 8;
  const float* px[8]; float acc[8];
#pragma unroll
  for (int r = 0; r < 8; r++) {
    int row = rb + r;
    px[r] = X + (size_t)row * 64;
    acc[r] = b1s[lane] + selfW[(size_t)(row / GN) * 64 + lane];
  }
#pragma unroll 8
  for (int k = 0; k < 64; k++) {
    float w = ws[k * 64 + lane];
#pragma unroll
    for (int r = 0; r < 8; r++) acc[r] = fmaf(px[r][k], w, acc[r]);
  }
  float bb2 = b2[0];
#pragma unroll
  for (int r = 0; r < 8; r++) {
    float v = fmaxf(acc[r], 0.f) * w2s[lane];
    v = wave_sum(v);
    int row = rb + r;
    if (lane == 0) sT[(size_t)(row % GN) * GB + row / GN] = v + bb2;
  }
}

// =============== 6. wsum hiS (fp32 ho) ===============
__global__ __launch_bounds__(256) void k_wsum_hiS(
    const float* __restrict__ ho, const float* __restrict__ sST,
    const float* __restrict__ linOW, const float* __restrict__ linOb,
    float* __restrict__ hiS) {
  __shared__ float ws[64 * 64];
  __shared__ float ts[4][64];
  int t = threadIdx.x, lane = t & 63, wave = t >> 6;
  for (int i = t; i < 4096; i += 256) ws[i] = linOW[i];
  __syncthreads();
  int b = blockIdx.x * 4 + wave;
  float acc = 0.f;
  for (int n = 0; n < GN; n++)
    acc = fmaf(sST[(size_t)n * GB + b], ho[((size_t)b * GN + n) * 64 + lane], acc);
  ts[wave][lane] = acc;
  float o = linOb[lane];
#pragma unroll 8
  for (int k = 0; k < 64; k++) o = fmaf(ts[wave][k], ws[k * 64 + lane], o);
  hiS[(size_t)b * 64 + lane] = fmaxf(o, 0.f);
}

// =============== 7. tail: um-MLP3 (MFMA) + final rating, fused ===============
__global__ __launch_bounds__(256, 2) void k_tail(
    const float* __restrict__ hiI, const float* __restrict__ hiS, const float* __restrict__ zj,
    const u16* __restrict__ um1t, const u16* __restrict__ um2t, const u16* __restrict__ um3t,
    const float* __restrict__ umb1, const float* __restrict__ umb2, const float* __restrict__ umb3,
    const float* __restrict__ gW1, const float* __restrict__ gb1,
    const float* __restrict__ gW2, const float* __restrict__ gb2,
    const float* __restrict__ gW3, const float* __restrict__ gb3,
    float* __restrict__ out) {
  __shared__ __align__(16) u16 xs[64 * 136], w1s[64 * 136], hs[64 * 72];
  __shared__ float b1s[64], b2s[64], b3s[64], g1s[128];
  int t = threadIdx.x;
  for (int i = t; i < 64 * 16; i += 256) { int n = i >> 4, j = i & 15;
    ((uint4*)(w1s + n * 136))[j] = ((const uint4*)(um1t + n * 128))[j]; }
  if (t < 64) { b1s[t] = umb1[t]; b2s[t] = umb2[t]; b3s[t] = umb3[t]; }
  if (t < 128) g1s[t] = gW1[t];
  int base = blockIdx.x * 64;
  { int lr = t >> 2, q = t & 3; int b = base + lr;
    const float* src = (q < 2) ? (hiI + (size_t)b * 64 + q * 32)
                               : (hiS + (size_t)b * 64 + (q - 2) * 32);
    u16* dst = xs + lr * 136 + q * 32;
#pragma unroll
    for (int h = 0; h < 8; h++) { float4 v = ((const float4*)src)[h]; ushort4 u;
      u.x = f2bf(v.x); u.y = f2bf(v.y); u.z = f2bf(v.z); u.w = f2bf(v.w);
      *(ushort4*)(dst + h * 4) = u; } }
  __syncthreads();
  const int lane = t & 63, wave = t >> 6, m = lane & 15, quad = lane >> 4;
  short8v w2f[8], w3f[8];
#pragma unroll
  for (int c = 0; c < 4; c++)
#pragma unroll
    for (int kk = 0; kk < 2; kk++) {
      int off = (c * 16 + m) * 64 + kk * 32 + quad * 8;
      w2f[c * 2 + kk] = *(const short8v*)(um2t + off);
      w3f[c * 2 + kk] = *(const short8v*)(um3t + off);
    }
  const f32x4 zz = {0.f, 0.f, 0.f, 0.f};
  f32x4 cc[4];
#pragma unroll
  for (int c = 0; c < 4; c++) cc[c] = zz;
#pragma unroll
  for (int kk = 0; kk < 4; kk++) {
    short8v av = *(const short8v*)(xs + (wave * 16 + m) * 136 + kk * 32 + quad * 8);
#pragma unroll
    for (int c = 0; c < 4; c++) {
      short8v bv = *(const short8v*)(w1s + (c * 16 + m) * 136 + kk * 32 + quad * 8);
      cc[c] = __builtin_amdgcn_mfma_f32_16x16x32_bf16(av, bv, cc[c], 0, 0, 0);
    }
  }
#pragma unroll
  for (int r = 0; r < 4; r++) { ushort4 u;
    u.x = f2bf(fmaxf(cc[0][r] + b1s[m], 0.f));
    u.y = f2bf(fmaxf(cc[1][r] + b1s[16 + m], 0.f));
    u.z = f2bf(fmaxf(cc[2][r] + b1s[32 + m], 0.f));
    u.w = f2bf(fmaxf(cc[3][r] + b1s[48 + m], 0.f));
    *(ushort4*)(hs + (wave * 16 + quad * 4 + r) * 72 + m * 4) = u; }
#pragma unroll
  for (int c = 0; c < 4; c++) cc[c] = zz;
#pragma unroll
  for (int kk = 0; kk < 2; kk++) {
    short8v av = *(const short8v*)(hs + (wave * 16 + m) * 72 + kk * 32 + quad * 8);
#pragma unroll
    for (int c = 0; c < 4; c++)
      cc[c] = __builtin_amdgcn_mfma_f32_16x16x32_bf16(av, w2f[c * 2 + kk], cc[c], 0, 0, 0);
  }
#pragma unroll
  for (int r = 0; r < 4; r++) { ushort4 u;
    u.x = f2bf(fmaxf(cc[0][r] + b2s[m], 0.f));
    u.y = f2bf(fmaxf(cc[1][r] + b2s[16 + m], 0.f));
    u.z = f2bf(fmaxf(cc[2][r] + b2s[32 + m], 0.f));
    u.w = f2bf(fmaxf(cc[3][r] + b2s[48 + m], 0.f));
    *(ushort4*)(hs + (wave * 16 + quad * 4 + r) * 72 + m * 4) = u; }
  f32x4 c3[4];
#pragma unroll
  for (int c = 0; c < 4; c++) c3[c] = zz;
#pragma unroll
  for (int kk = 0; kk < 2; kk++) {
    short8v av = *(const short8v*)(hs + (wave * 16 + m) * 72 + kk * 32 + quad * 8);
#pragma unroll
    for (int c = 0; c < 4; c++)
      c3[c] = __builtin_amdgcn_mfma_f32_16x16x32_bf16(av, w3f[c * 2 + kk], c3[c], 0, 0, 0);
  }
#pragma unroll
  for (int r = 0; r < 4; r++) { ushort4 u;
    u.x = f2bf(c3[0][r] + b3s[m]);
    u.y = f2bf(c3[1][r] + b3s[16 + m]);
    u.z = f2bf(c3[2][r] + b3s[32 + m]);
    u.w = f2bf(c3[3][r] + b3s[48 + m]);
    *(ushort4*)(hs + (wave * 16 + quad * 4 + r) * 72 + m * 4) = u; }
  // final rating for this wave's 16 rows
  float gb1v = gb1[0], gb2v = gb2[0], gb3v = gb3[0], gW2v = gW2[0], gW3v = gW3[0];
  int px = IDX16(lane);
  for (int r16 = 0; r16 < 16; r16++) {
    int row = wave * 16 + r16, b = base + row;
    float v = bf2f(hs[row * 72 + px]) * g1s[lane] + zj[(size_t)b * 64 + lane] * g1s[64 + lane];
    v = wave_sum(v);
    if (lane == 0) {
      float h = fmaxf(v + gb1v, 0.f);
      h = fmaxf(h * gW2v + gb2v, 0.f);
      out[b] = h * gW3v + gb3v;
    }
  }
}

extern "C" void kernel_launch(void* const* d_in, const int* in_sizes, int n_in,
                              void* d_out, int out_size, void* d_ws, size_t ws_size,
                              hipStream_t stream) {
  const float* E_u = (const float*)d_in[0];
  const float* E_i = (const float*)d_in[1];
  const float* E_r = (const float*)d_in[2];
  const float* gvW1 = (const float*)d_in[3];  const float* gvb1 = (const float*)d_in[4];
  const float* gvW2 = (const float*)d_in[5];  const float* gvb2 = (const float*)d_in[6];
  const float* gvW3 = (const float*)d_in[7];  const float* gvb3 = (const float*)d_in[8];
  const float* umW1 = (const float*)d_in[9];  const float* umb1 = (const float*)d_in[10];
  const float* umW2 = (const float*)d_in[11]; const float* umb2 = (const float*)d_in[12];
  const float* umW3 = (const float*)d_in[13]; const float* umb3 = (const float*)d_in[14];
  const float* guW1 = (const float*)d_in[15]; const float* gub1 = (const float*)d_in[16];
  const float* guW2 = (const float*)d_in[17]; const float* gub2 = (const float*)d_in[18];
  const float* guW3 = (const float*)d_in[19]; const float* gub3 = (const float*)d_in[20];
  const float* aIW1 = (const float*)d_in[21]; const float* aIb1 = (const float*)d_in[22];
  const float* aIW2 = (const float*)d_in[23]; const float* aIb2 = (const float*)d_in[24];
  const float* aOW1 = (const float*)d_in[25]; const float* aOb1 = (const float*)d_in[26];
  const float* aOW2 = (const float*)d_in[27]; const float* aOb2 = (const float*)d_in[28];
  const float* aSW1 = (const float*)d_in[29]; const float* aSb1 = (const float*)d_in[30];
  const float* aSW2 = (const float*)d_in[31]; const float* aSb2 = (const float*)d_in[32];
  const float* aiW1 = (const float*)d_in[33]; const float* aib1 = (const float*)d_in[34];
  const float* aiW2 = (const float*)d_in[35]; const float* aib2 = (const float*)d_in[36];
  const float* linIW = (const float*)d_in[37]; const float* linIb = (const float*)d_in[38];
  const float* linOW = (const float*)d_in[39]; const float* linOb = (const float*)d_in[40];
  const float* ilinW = (const float*)d_in[41]; const float* ilinb = (const float*)d_in[42];
  const float* gW1 = (const float*)d_in[43]; const float* gb1 = (const float*)d_in[44];
  const float* gW2 = (const float*)d_in[45]; const float* gb2 = (const float*)d_in[46];
  const float* gW3 = (const float*)d_in[47]; const float* gb3 = (const float*)d_in[48];
  const int* nodes_u = (const int*)d_in[49];
  const int* nodes_i = (const int*)d_in[50];
  const int* u_items = (const int*)d_in[51];
  const int* u_users = (const int*)d_in[52];
  const int* i_users = (const int*)d_in[53];
  const int* u_items_r = (const int*)d_in[54];
  const int* uu_items = (const int*)d_in[55];
  const int* uu_items_r = (const int*)d_in[56];
  const int* i_users_r = (const int*)d_in[57];
  float* out = (float*)d_out;

  const int BN = GB * GN;        // 15360
  const int M2 = GB * GN * GN;   // 460800

  float* p = (float*)d_ws;
  float* piWI = p; p += GB * GD;
  float* piWS = p; p += GB * GD;
  float* qjWi = p; p += GB * GD;
  float* poW  = p; p += BN * GD;
  float* ho   = p; p += BN * GD;
  float* sIT  = p; p += BN;
  float* siT  = p; p += BN;
  float* sST  = p; p += BN;
  float* sOT  = p; p += M2;
  float* hiI  = p; p += GB * GD;
  float* hiS  = p; p += GB * GD;
  float* zj   = p; p += GB * GD;
  u16* q16 = (u16*)p;
  u16* gv1t = q16; q16 += 8192;
  u16* gv2t = q16; q16 += 4096;
  u16* gv3t = q16; q16 += 4096;
  u16* gu1t = q16; q16 += 8192;
  u16* gu2t = q16; q16 += 4096;
  u16* gu3t = q16; q16 += 4096;
  u16* um1t = q16; q16 += 8192;
  u16* um2t = q16; q16 += 4096;
  u16* um3t = q16; q16 += 4096;
  u16* aOt  = q16; q16 += 4096;
  u16* aIt  = q16; q16 += 4096;
  u16* ait  = q16; q16 += 4096;
  u16* xia_bf = q16; q16 += (size_t)BN * GD;
  u16* fjt_bf = q16; q16 += (size_t)BN * GD;
  u16* xoa_bf = q16; q16 += (size_t)M2 * GD;   // 59 MB

  k_setup<<<768, 256, 0, stream>>>(gvW1, gvW2, gvW3, guW1, guW2, guW3,
                                   umW1, umW2, umW3, aOW1, aIW1, aiW1, aSW1,
                                   E_u, E_i, nodes_u, nodes_i, u_users,
                                   gv1t, gv2t, gv3t, gu1t, gu2t, gu3t,
                                   um1t, um2t, um3t, aOt, aIt, ait,
                                   piWI, piWS, qjWi, poW);
  k_engine<<<512, 256, 0, stream>>>(E_i, E_r, E_u,
                                    uu_items, uu_items_r, u_items, u_items_r,
                                    i_users, i_users_r,
                                    gv1t, gv2t, gv3t, gu1t, gu2t, gu3t,
                                    gvb1, gvb2, gvb3, gub1, gub2, gub3,
                                    aOt, aIt, ait, aOb1, aIb1, aib1,
                                    aOW2, aIW2, aiW2, aOb2, aIb2, aib2,
                                    poW, piWI, qjWi,
                                    xoa_bf, xia_bf, fjt_bf, sOT, sIT, siT);
  k_softmax_t<<<960, 256, 0, stream>>>(sIT, siT, sOT);
  k_agg<<<256 + BN / 4, 256, 0, stream>>>(xia_bf, fjt_bf, xoa_bf, sIT, siT, sOT,
                                          linIW, linIb, ilinW, ilinb, linOW, linOb,
                                          hiI, zj, ho);
  k_score_sS<<<BN / 32, 256, 0, stream>>>(piWS, ho, aSW1 + 64 * 64, aSb1, aSW2, aSb2, sST);
  k_softmax_t<<<30, 256, 0, stream>>>(sST, sST, sST);
  k_wsum_hiS<<<GB / 4, 256, 0, stream>>>(ho, sST, linOW, linOb, hiS);
  k_tail<<<GB / 64, 256, 0, stream>>>(hiI, hiS, zj, um1t, um2t, um3t,
                                      umb1, umb2, umb3,
                                      gW1, gb1, gW2, gb2, gW3, gb3, out);
}